// Round 1
// baseline (4997.430 us; speedup 1.0000x reference)
//
#include <hip/hip_runtime.h>
#include <math.h>

#define N_EMBD   1024
#define N_HEAD   16
#define HEAD_DIM 64
#define BATCH    2
#define TSEQ     2048
#define RANK     16
#define LORA_SCALE 2.0f
#define M_TOTAL  (BATCH * TSEQ)   // 4096
#define C3       (3 * N_EMBD)     // 3072

__device__ __forceinline__ float fake_quant(float x, float scale, float zp) {
    float q = rintf(x / scale + zp);          // round half-to-even, matches jnp.round
    q = fminf(fmaxf(q, 0.0f), 255.0f);
    return (q - zp) * scale;
}

// t[M,16] = x[M,K] @ la[K,16]
__global__ void lora_t_kernel(const float* __restrict__ x,
                              const float* __restrict__ la,
                              float* __restrict__ t, int K) {
    __shared__ float Xs[16][64];
    const int tid = threadIdx.x;              // 256
    const int ty = tid >> 4, tx = tid & 15;   // row, col
    const int row0 = blockIdx.x * 16;
    float acc = 0.0f;
    for (int k0 = 0; k0 < K; k0 += 64) {
        for (int r = 0; r < 4; ++r) {
            int idx = r * 256 + tid;
            int rr = idx >> 6, kk = idx & 63;
            Xs[rr][kk] = x[(size_t)(row0 + rr) * K + k0 + kk];
        }
        __syncthreads();
        for (int kk = 0; kk < 64; ++kk)
            acc += Xs[ty][kk] * la[(size_t)(k0 + kk) * RANK + tx];
        __syncthreads();
    }
    t[(size_t)(row0 + ty) * RANK + tx] = acc;
}

// C[M,N] = A[M,K] @ W[K,N] + bias[N] + LORA_SCALE * (t[M,16] @ lb[16,N])
// 64x64 block tile, 256 threads, 4x4 micro-tile per thread, K-tile 16.
__global__ void gemm_lora_kernel(const float* __restrict__ A,
                                 const float* __restrict__ W,
                                 const float* __restrict__ bias,
                                 const float* __restrict__ t,
                                 const float* __restrict__ lb,
                                 float* __restrict__ C,
                                 int M, int N, int K) {
    __shared__ float As[64][16];
    __shared__ float Bs[16][64];
    __shared__ float Ts[64][16];
    __shared__ float Ls[16][64];
    const int tid = threadIdx.x;              // 256
    const int tx = tid & 15, ty = tid >> 4;
    const int row0 = blockIdx.y * 64, col0 = blockIdx.x * 64;
    float c[4][4] = {};
    for (int k0 = 0; k0 < K; k0 += 16) {
        for (int r = 0; r < 4; ++r) {
            int idx = r * 256 + tid;
            int ar = idx >> 4, ak = idx & 15;
            As[ar][ak] = A[(size_t)(row0 + ar) * K + k0 + ak];
            int br = idx >> 6, bc = idx & 63;
            Bs[br][bc] = W[(size_t)(k0 + br) * N + col0 + bc];
        }
        __syncthreads();
        for (int kk = 0; kk < 16; ++kk) {
            float a[4], b[4];
            #pragma unroll
            for (int i = 0; i < 4; ++i) a[i] = As[ty + 16 * i][kk];
            #pragma unroll
            for (int j = 0; j < 4; ++j) b[j] = Bs[kk][tx + 16 * j];
            #pragma unroll
            for (int i = 0; i < 4; ++i)
                #pragma unroll
                for (int j = 0; j < 4; ++j)
                    c[i][j] += a[i] * b[j];
        }
        __syncthreads();
    }
    // epilogue: bias + LoRA rank-16 correction
    for (int r = 0; r < 4; ++r) {
        int idx = r * 256 + tid;
        int ar = idx >> 4, ak = idx & 15;
        Ts[ar][ak] = t[(size_t)(row0 + ar) * RANK + ak];
        int br = idx >> 6, bc = idx & 63;
        Ls[br][bc] = lb[(size_t)br * N + col0 + bc];
    }
    __syncthreads();
    #pragma unroll
    for (int i = 0; i < 4; ++i) {
        int row = row0 + ty + 16 * i;
        #pragma unroll
        for (int j = 0; j < 4; ++j) {
            int col = col0 + tx + 16 * j;
            float l = 0.0f;
            #pragma unroll
            for (int r = 0; r < RANK; ++r)
                l += Ts[ty + 16 * i][r] * Ls[r][tx + 16 * j];
            C[(size_t)row * N + col] = c[i][j] + bias[col] + LORA_SCALE * l;
        }
    }
}

// One block (256 thr) per (b, h, query-row). Causal softmax over fake-quant K/V.
__global__ void attn_kernel(const float* __restrict__ qkv,   // [B,T,3C]
                            const float* __restrict__ scale_p,
                            const float* __restrict__ zp_p,
                            float* __restrict__ out) {        // [B,T,C]
    const int qi = blockIdx.x;
    const int h  = blockIdx.y;
    const int b  = blockIdx.z;
    const int tid = threadIdx.x;              // 256
    const float scale = scale_p[0];
    const float zp    = zp_p[0];
    __shared__ float qs[HEAD_DIM];
    __shared__ float sc[TSEQ];
    __shared__ float red[256];
    __shared__ float part[4][HEAD_DIM];
    const float* base = qkv + (size_t)b * TSEQ * C3;
    if (tid < HEAD_DIM)
        qs[tid] = base[(size_t)qi * C3 + h * HEAD_DIM + tid];
    __syncthreads();
    const int nk = qi + 1;
    // scores
    for (int j = tid; j < nk; j += 256) {
        const float* krow = base + (size_t)j * C3 + N_EMBD + h * HEAD_DIM;
        float s = 0.0f;
        #pragma unroll 8
        for (int d = 0; d < HEAD_DIM; ++d)
            s += qs[d] * fake_quant(krow[d], scale, zp);
        sc[j] = s * 0.125f;                   // 1/sqrt(64)
    }
    // max reduce
    float m = -INFINITY;
    for (int j = tid; j < nk; j += 256) m = fmaxf(m, sc[j]);
    red[tid] = m;
    __syncthreads();
    for (int s2 = 128; s2 > 0; s2 >>= 1) {
        if (tid < s2) red[tid] = fmaxf(red[tid], red[tid + s2]);
        __syncthreads();
    }
    m = red[0];
    __syncthreads();
    // exp + sum
    float lsum = 0.0f;
    for (int j = tid; j < nk; j += 256) {
        float p = expf(sc[j] - m);
        sc[j] = p;
        lsum += p;
    }
    red[tid] = lsum;
    __syncthreads();
    for (int s2 = 128; s2 > 0; s2 >>= 1) {
        if (tid < s2) red[tid] += red[tid + s2];
        __syncthreads();
    }
    const float denom = red[0];
    // output: 64 dims x 4 groups
    const int d = tid & 63, g = tid >> 6;
    float acc = 0.0f;
    for (int j = g; j < nk; j += 4) {
        const float* vrow = base + (size_t)j * C3 + 2 * N_EMBD + h * HEAD_DIM;
        acc += sc[j] * fake_quant(vrow[d], scale, zp);
    }
    part[g][d] = acc;
    __syncthreads();
    if (g == 0) {
        float o = (part[0][d] + part[1][d] + part[2][d] + part[3][d]) / denom;
        out[((size_t)b * TSEQ + qi) * N_EMBD + h * HEAD_DIM + d] = o;
    }
}

extern "C" void kernel_launch(void* const* d_in, const int* in_sizes, int n_in,
                              void* d_out, int out_size, void* d_ws, size_t ws_size,
                              hipStream_t stream) {
    const float* x        = (const float*)d_in[0];
    const float* w_attn   = (const float*)d_in[1];
    const float* b_attn   = (const float*)d_in[2];
    const float* la_attn  = (const float*)d_in[3];
    const float* lb_attn  = (const float*)d_in[4];
    const float* w_proj   = (const float*)d_in[5];
    const float* b_proj   = (const float*)d_in[6];
    const float* la_proj  = (const float*)d_in[7];
    const float* lb_proj  = (const float*)d_in[8];
    const float* kv_scale = (const float*)d_in[9];
    const float* kv_zp    = (const float*)d_in[10];
    float* out = (float*)d_out;

    float* qkv      = (float*)d_ws;                              // 4096*3072
    float* t_attn   = qkv + (size_t)M_TOTAL * C3;                // 4096*16
    float* attn_out = t_attn + (size_t)M_TOTAL * RANK;           // 4096*1024
    float* t_proj   = attn_out + (size_t)M_TOTAL * N_EMBD;       // 4096*16

    lora_t_kernel<<<dim3(M_TOTAL / 16), 256, 0, stream>>>(x, la_attn, t_attn, N_EMBD);
    gemm_lora_kernel<<<dim3(C3 / 64, M_TOTAL / 64), 256, 0, stream>>>(
        x, w_attn, b_attn, t_attn, lb_attn, qkv, M_TOTAL, C3, N_EMBD);
    attn_kernel<<<dim3(TSEQ, N_HEAD, BATCH), 256, 0, stream>>>(
        qkv, kv_scale, kv_zp, attn_out);
    lora_t_kernel<<<dim3(M_TOTAL / 16), 256, 0, stream>>>(attn_out, la_proj, t_proj, N_EMBD);
    gemm_lora_kernel<<<dim3(N_EMBD / 64, M_TOTAL / 64), 256, 0, stream>>>(
        attn_out, w_proj, b_proj, t_proj, lb_proj, out, M_TOTAL, N_EMBD, N_EMBD);
}

// Round 2
// 1662.265 us; speedup vs baseline: 3.0064x; 3.0064x over previous
//
#include <hip/hip_runtime.h>
#include <math.h>

#define N_EMBD   1024
#define N_HEAD   16
#define HEAD_DIM 64
#define BATCH    2
#define TSEQ     2048
#define RANK     16
#define LORA_SCALE 2.0f
#define M_TOTAL  (BATCH * TSEQ)   // 4096
#define C3       (3 * N_EMBD)     // 3072
#define PAD      68               // 64 + 4: float4-aligned, bank-conflict-breaking

__device__ __forceinline__ float fake_quant(float x, float scale, float zp) {
    float q = rintf(x / scale + zp);          // round half-to-even, matches jnp.round
    q = fminf(fmaxf(q, 0.0f), 255.0f);
    return (q - zp) * scale;
}

// t[M,16] = x[M,K] @ la[K,16]
__global__ void lora_t_kernel(const float* __restrict__ x,
                              const float* __restrict__ la,
                              float* __restrict__ t, int K) {
    __shared__ float Xs[16][64];
    const int tid = threadIdx.x;              // 256
    const int ty = tid >> 4, tx = tid & 15;   // row, col
    const int row0 = blockIdx.x * 16;
    float acc = 0.0f;
    for (int k0 = 0; k0 < K; k0 += 64) {
        for (int r = 0; r < 4; ++r) {
            int idx = r * 256 + tid;
            int rr = idx >> 6, kk = idx & 63;
            Xs[rr][kk] = x[(size_t)(row0 + rr) * K + k0 + kk];
        }
        __syncthreads();
        for (int kk = 0; kk < 64; ++kk)
            acc += Xs[ty][kk] * la[(size_t)(k0 + kk) * RANK + tx];
        __syncthreads();
    }
    t[(size_t)(row0 + ty) * RANK + tx] = acc;
}

// C[M,N] = A[M,K] @ W[K,N] + bias[N] + LORA_SCALE * (t[M,16] @ lb[16,N])
__global__ void gemm_lora_kernel(const float* __restrict__ A,
                                 const float* __restrict__ W,
                                 const float* __restrict__ bias,
                                 const float* __restrict__ t,
                                 const float* __restrict__ lb,
                                 float* __restrict__ C,
                                 int M, int N, int K) {
    __shared__ float As[64][16];
    __shared__ float Bs[16][64];
    __shared__ float Ts[64][16];
    __shared__ float Ls[16][64];
    const int tid = threadIdx.x;              // 256
    const int tx = tid & 15, ty = tid >> 4;
    const int row0 = blockIdx.y * 64, col0 = blockIdx.x * 64;
    float c[4][4] = {};
    for (int k0 = 0; k0 < K; k0 += 16) {
        for (int r = 0; r < 4; ++r) {
            int idx = r * 256 + tid;
            int ar = idx >> 4, ak = idx & 15;
            As[ar][ak] = A[(size_t)(row0 + ar) * K + k0 + ak];
            int br = idx >> 6, bc = idx & 63;
            Bs[br][bc] = W[(size_t)(k0 + br) * N + col0 + bc];
        }
        __syncthreads();
        for (int kk = 0; kk < 16; ++kk) {
            float a[4], b[4];
            #pragma unroll
            for (int i = 0; i < 4; ++i) a[i] = As[ty + 16 * i][kk];
            #pragma unroll
            for (int j = 0; j < 4; ++j) b[j] = Bs[kk][tx + 16 * j];
            #pragma unroll
            for (int i = 0; i < 4; ++i)
                #pragma unroll
                for (int j = 0; j < 4; ++j)
                    c[i][j] += a[i] * b[j];
        }
        __syncthreads();
    }
    for (int r = 0; r < 4; ++r) {
        int idx = r * 256 + tid;
        int ar = idx >> 4, ak = idx & 15;
        Ts[ar][ak] = t[(size_t)(row0 + ar) * RANK + ak];
        int br = idx >> 6, bc = idx & 63;
        Ls[br][bc] = lb[(size_t)br * N + col0 + bc];
    }
    __syncthreads();
    #pragma unroll
    for (int i = 0; i < 4; ++i) {
        int row = row0 + ty + 16 * i;
        #pragma unroll
        for (int j = 0; j < 4; ++j) {
            int col = col0 + tx + 16 * j;
            float l = 0.0f;
            #pragma unroll
            for (int r = 0; r < RANK; ++r)
                l += Ts[ty + 16 * i][r] * Ls[r][tx + 16 * j];
            C[(size_t)row * N + col] = c[i][j] + bias[col] + LORA_SCALE * l;
        }
    }
}

// Flash attention: one block per (b, h, 64-row q-tile). fp32 vector ALU.
// fake_quant applied once per staged K/V element. V transposed in LDS so
// both matmuls do float4 x float4 dot-accumulate from LDS.
__global__ __launch_bounds__(256, 2)
void flash_attn_kernel(const float* __restrict__ qkv,   // [B,T,3C]
                       const float* __restrict__ scale_p,
                       const float* __restrict__ zp_p,
                       float* __restrict__ out) {        // [B,T,C]
    const int qt = blockIdx.x;    // q-tile 0..31
    const int h  = blockIdx.y;
    const int b  = blockIdx.z;
    const int tid = threadIdx.x;  // 256
    const int tx = tid & 15, ty = tid >> 4;
    const float scale = scale_p[0];
    const float zp    = zp_p[0];

    __shared__ float Qs[64][PAD];
    __shared__ float Ks[64][PAD];
    __shared__ float Vt[64][PAD];   // transposed: Vt[d][k]
    __shared__ float Ps[64][PAD];
    __shared__ float m_sh[64], l_sh[64], alpha_sh[64];
    __shared__ float red[64][4];

    const float* base = qkv + (size_t)b * TSEQ * C3;

    // stage Q tile, folding 1/sqrt(64) = 0.125 (exact pow2 multiply)
    #pragma unroll
    for (int r = 0; r < 4; ++r) {
        int j = r * 256 + tid;       // 0..1023 -> (row, d4)
        int row = j >> 4;
        int d4  = (j & 15) * 4;
        const float4 v = *(const float4*)(base + (size_t)(qt * 64 + row) * C3 + h * 64 + d4);
        Qs[row][d4 + 0] = v.x * 0.125f;
        Qs[row][d4 + 1] = v.y * 0.125f;
        Qs[row][d4 + 2] = v.z * 0.125f;
        Qs[row][d4 + 3] = v.w * 0.125f;
    }
    if (tid < 64) { m_sh[tid] = -INFINITY; l_sh[tid] = 0.0f; }

    float o[4][4] = {};

    for (int kt = 0; kt <= qt; ++kt) {
        __syncthreads();   // previous tile's Ks/Vt readers done
        // stage fake-quanted K tile and transposed V tile
        #pragma unroll
        for (int r = 0; r < 4; ++r) {
            int j = r * 256 + tid;
            int row = j >> 4;
            int d4  = (j & 15) * 4;
            const float4 kv = *(const float4*)(base + (size_t)(kt * 64 + row) * C3 + N_EMBD + h * 64 + d4);
            Ks[row][d4 + 0] = fake_quant(kv.x, scale, zp);
            Ks[row][d4 + 1] = fake_quant(kv.y, scale, zp);
            Ks[row][d4 + 2] = fake_quant(kv.z, scale, zp);
            Ks[row][d4 + 3] = fake_quant(kv.w, scale, zp);
            const float4 vv = *(const float4*)(base + (size_t)(kt * 64 + row) * C3 + 2 * N_EMBD + h * 64 + d4);
            Vt[d4 + 0][row] = fake_quant(vv.x, scale, zp);
            Vt[d4 + 1][row] = fake_quant(vv.y, scale, zp);
            Vt[d4 + 2][row] = fake_quant(vv.z, scale, zp);
            Vt[d4 + 3][row] = fake_quant(vv.w, scale, zp);
        }
        __syncthreads();

        // S = Q @ K^T   (4x4 micro-tile per thread, float4 dot over d)
        float s[4][4] = {};
        for (int d0 = 0; d0 < 64; d0 += 4) {
            float4 a4[4], b4[4];
            #pragma unroll
            for (int i = 0; i < 4; ++i) a4[i] = *(const float4*)&Qs[ty + 16 * i][d0];
            #pragma unroll
            for (int j = 0; j < 4; ++j) b4[j] = *(const float4*)&Ks[tx + 16 * j][d0];
            #pragma unroll
            for (int i = 0; i < 4; ++i)
                #pragma unroll
                for (int j = 0; j < 4; ++j)
                    s[i][j] += a4[i].x * b4[j].x + a4[i].y * b4[j].y
                             + a4[i].z * b4[j].z + a4[i].w * b4[j].w;
        }
        // causal mask (only the diagonal tile is partial) + publish scores
        const bool diag = (kt == qt);
        #pragma unroll
        for (int i = 0; i < 4; ++i)
            #pragma unroll
            for (int j = 0; j < 4; ++j) {
                float v = s[i][j];
                if (diag && (tx + 16 * j > ty + 16 * i)) v = -INFINITY;
                Ps[ty + 16 * i][tx + 16 * j] = v;
            }
        __syncthreads();

        // online softmax: row max
        const int r  = tid >> 2;      // row 0..63
        const int q4 = tid & 3;       // quarter
        float lm = -INFINITY;
        for (int k = q4 * 16; k < q4 * 16 + 16; ++k) lm = fmaxf(lm, Ps[r][k]);
        red[r][q4] = lm;
        __syncthreads();
        if (tid < 64) {
            float tm = fmaxf(fmaxf(red[tid][0], red[tid][1]),
                             fmaxf(red[tid][2], red[tid][3]));
            float mo = m_sh[tid];
            float mn = fmaxf(mo, tm);
            m_sh[tid] = mn;
            alpha_sh[tid] = __expf(mo - mn);   // -inf -> 0 on first tile
        }
        __syncthreads();
        // exponentiate + partial row sums
        float ls = 0.0f;
        {
            const float mn = m_sh[r];
            for (int k = q4 * 16; k < q4 * 16 + 16; ++k) {
                float p = __expf(Ps[r][k] - mn);
                Ps[r][k] = p;
                ls += p;
            }
        }
        red[r][q4] = ls;
        __syncthreads();
        if (tid < 64)
            l_sh[tid] = alpha_sh[tid] * l_sh[tid]
                      + red[tid][0] + red[tid][1] + red[tid][2] + red[tid][3];

        // rescale accumulator, then O += P @ V
        float al[4];
        #pragma unroll
        for (int i = 0; i < 4; ++i) al[i] = alpha_sh[ty + 16 * i];
        #pragma unroll
        for (int i = 0; i < 4; ++i)
            #pragma unroll
            for (int j = 0; j < 4; ++j) o[i][j] *= al[i];

        for (int k0 = 0; k0 < 64; k0 += 4) {
            float4 a4[4], b4[4];
            #pragma unroll
            for (int i = 0; i < 4; ++i) a4[i] = *(const float4*)&Ps[ty + 16 * i][k0];
            #pragma unroll
            for (int j = 0; j < 4; ++j) b4[j] = *(const float4*)&Vt[tx + 16 * j][k0];
            #pragma unroll
            for (int i = 0; i < 4; ++i)
                #pragma unroll
                for (int j = 0; j < 4; ++j)
                    o[i][j] += a4[i].x * b4[j].x + a4[i].y * b4[j].y
                             + a4[i].z * b4[j].z + a4[i].w * b4[j].w;
        }
    }
    __syncthreads();   // last l_sh update visible

    #pragma unroll
    for (int i = 0; i < 4; ++i) {
        const int q = ty + 16 * i;
        const float inv_l = 1.0f / l_sh[q];
        #pragma unroll
        for (int j = 0; j < 4; ++j) {
            const int d = tx + 16 * j;
            out[((size_t)b * TSEQ + qt * 64 + q) * N_EMBD + h * 64 + d] = o[i][j] * inv_l;
        }
    }
}

extern "C" void kernel_launch(void* const* d_in, const int* in_sizes, int n_in,
                              void* d_out, int out_size, void* d_ws, size_t ws_size,
                              hipStream_t stream) {
    const float* x        = (const float*)d_in[0];
    const float* w_attn   = (const float*)d_in[1];
    const float* b_attn   = (const float*)d_in[2];
    const float* la_attn  = (const float*)d_in[3];
    const float* lb_attn  = (const float*)d_in[4];
    const float* w_proj   = (const float*)d_in[5];
    const float* b_proj   = (const float*)d_in[6];
    const float* la_proj  = (const float*)d_in[7];
    const float* lb_proj  = (const float*)d_in[8];
    const float* kv_scale = (const float*)d_in[9];
    const float* kv_zp    = (const float*)d_in[10];
    float* out = (float*)d_out;

    float* qkv      = (float*)d_ws;                              // 4096*3072
    float* t_attn   = qkv + (size_t)M_TOTAL * C3;                // 4096*16
    float* attn_out = t_attn + (size_t)M_TOTAL * RANK;           // 4096*1024
    float* t_proj   = attn_out + (size_t)M_TOTAL * N_EMBD;       // 4096*16

    lora_t_kernel<<<dim3(M_TOTAL / 16), 256, 0, stream>>>(x, la_attn, t_attn, N_EMBD);
    gemm_lora_kernel<<<dim3(C3 / 64, M_TOTAL / 64), 256, 0, stream>>>(
        x, w_attn, b_attn, t_attn, lb_attn, qkv, M_TOTAL, C3, N_EMBD);
    flash_attn_kernel<<<dim3(TSEQ / 64, N_HEAD, BATCH), 256, 0, stream>>>(
        qkv, kv_scale, kv_zp, attn_out);
    lora_t_kernel<<<dim3(M_TOTAL / 16), 256, 0, stream>>>(attn_out, la_proj, t_proj, N_EMBD);
    gemm_lora_kernel<<<dim3(N_EMBD / 64, M_TOTAL / 64), 256, 0, stream>>>(
        attn_out, w_proj, b_proj, t_proj, lb_proj, out, M_TOTAL, N_EMBD, N_EMBD);
}

// Round 3
// 1252.494 us; speedup vs baseline: 3.9900x; 1.3272x over previous
//
#include <hip/hip_runtime.h>
#include <hip/hip_bf16.h>
#include <math.h>

#define N_EMBD   1024
#define N_HEAD   16
#define HEAD_DIM 64
#define BATCH    2
#define TSEQ     2048
#define RANK     16
#define LORA_SCALE 2.0f
#define M_TOTAL  (BATCH * TSEQ)   // 4096
#define C3       (3 * N_EMBD)     // 3072
#define PAD      68

typedef __attribute__((ext_vector_type(8))) short bf16x8;
typedef __attribute__((ext_vector_type(4))) float f32x4;

__device__ __forceinline__ float fake_quant(float x, float scale, float zp) {
    float q = rintf(x / scale + zp);
    q = fminf(fmaxf(q, 0.0f), 255.0f);
    return (q - zp) * scale;
}

__device__ __forceinline__ float bfraw2f(unsigned short u) {
    union { unsigned int i; float f; } c; c.i = ((unsigned int)u) << 16; return c.f;
}

// ---------------- conversion kernels ----------------
__global__ void cvt_split_kernel(const float* __restrict__ in,
                                 __hip_bfloat16* __restrict__ hi,
                                 __hip_bfloat16* __restrict__ lo, int n4) {
    int i = blockIdx.x * 256 + threadIdx.x;
    if (i >= n4) return;
    float4 v = ((const float4*)in)[i];
    float vs[4] = {v.x, v.y, v.z, v.w};
    #pragma unroll
    for (int k = 0; k < 4; ++k) {
        __hip_bfloat16 h = __float2bfloat16(vs[k]);
        hi[i * 4 + k] = h;
        lo[i * 4 + k] = __float2bfloat16(vs[k] - __bfloat162float(h));
    }
}

// in [R][C] fp32 -> outT [C][R] bf16 hi/lo
__global__ void transpose_split_kernel(const float* __restrict__ in,
                                       __hip_bfloat16* __restrict__ hiT,
                                       __hip_bfloat16* __restrict__ loT,
                                       int R, int C) {
    __shared__ float tl[32][33];
    const int c0 = blockIdx.x * 32, r0 = blockIdx.y * 32;
    const int tx = threadIdx.x & 31, ty = threadIdx.x >> 5;
    for (int i = ty; i < 32; i += 8)
        tl[i][tx] = in[(size_t)(r0 + i) * C + c0 + tx];
    __syncthreads();
    for (int i = ty; i < 32; i += 8) {
        float v = tl[tx][i];
        __hip_bfloat16 h = __float2bfloat16(v);
        size_t o = (size_t)(c0 + i) * R + r0 + tx;
        hiT[o] = h;
        if (loT) loT[o] = __float2bfloat16(v - __bfloat162float(h));
    }
}

// ---------------- LoRA rank-16 projections ----------------
__global__ void lora_t_kernel(const float* __restrict__ x,
                              const float* __restrict__ la,
                              float* __restrict__ t, int K) {
    __shared__ float Xs[16][64];
    const int tid = threadIdx.x;
    const int ty = tid >> 4, tx = tid & 15;
    const int row0 = blockIdx.x * 16;
    float acc = 0.0f;
    for (int k0 = 0; k0 < K; k0 += 64) {
        int e = tid * 4, rr = e >> 6, kk = e & 63;
        float4 v = *(const float4*)(x + (size_t)(row0 + rr) * K + k0 + kk);
        Xs[rr][kk] = v.x; Xs[rr][kk + 1] = v.y; Xs[rr][kk + 2] = v.z; Xs[rr][kk + 3] = v.w;
        __syncthreads();
        for (int k = 0; k < 64; ++k)
            acc += Xs[ty][k] * la[(size_t)(k0 + k) * RANK + tx];
        __syncthreads();
    }
    t[(size_t)(row0 + ty) * RANK + tx] = acc;
}

__global__ void lora_t_bf16_kernel(const __hip_bfloat16* __restrict__ x,
                                   const float* __restrict__ la,
                                   float* __restrict__ t, int K) {
    __shared__ float Xs[16][64];
    const int tid = threadIdx.x;
    const int ty = tid >> 4, tx = tid & 15;
    const int row0 = blockIdx.x * 16;
    float acc = 0.0f;
    for (int k0 = 0; k0 < K; k0 += 64) {
        int e = tid * 4, rr = e >> 6, kk = e & 63;
        const ushort4 u = *(const ushort4*)((const unsigned short*)x + (size_t)(row0 + rr) * K + k0 + kk);
        Xs[rr][kk] = bfraw2f(u.x); Xs[rr][kk + 1] = bfraw2f(u.y);
        Xs[rr][kk + 2] = bfraw2f(u.z); Xs[rr][kk + 3] = bfraw2f(u.w);
        __syncthreads();
        for (int k = 0; k < 64; ++k)
            acc += Xs[ty][k] * la[(size_t)(k0 + k) * RANK + tx];
        __syncthreads();
    }
    t[(size_t)(row0 + ty) * RANK + tx] = acc;
}

// ---------------- MFMA GEMM ----------------
// C[M,N] = A @ B^T + bias + LORA_SCALE*(t @ lb);  A[M][K], Bt[N][K] bf16 (hi/lo).
// 128x128 tile, BK=32, 4 waves (2x2 of 64x64), 16x16x32 MFMA.
// XOR-swizzled LDS tiles staged via global_load_lds width=16.
__device__ __forceinline__ int sw_off(int r, int c) {   // byte offset, tile 128x32 bf16
    return ((r >> 1) << 7) + (((((r & 1) << 2) | c) ^ ((r >> 1) & 7)) << 4);
}

template <bool SPLIT>
__global__ __launch_bounds__(256)
void gemm_mfma_kernel(const __hip_bfloat16* __restrict__ Ah,
                      const __hip_bfloat16* __restrict__ Al,
                      const __hip_bfloat16* __restrict__ Bh,
                      const __hip_bfloat16* __restrict__ Bl,
                      const float* __restrict__ bias,
                      const float* __restrict__ t,
                      const float* __restrict__ lb,
                      float* __restrict__ C,
                      int M, int N, int K) {
    constexpr int TILE = 128 * 32;              // bf16 elements per tile
    __shared__ __hip_bfloat16 As[SPLIT ? 2 * TILE : TILE];
    __shared__ __hip_bfloat16 Bs[SPLIT ? 2 * TILE : TILE];
    __shared__ float Ts[128 * 16];
    __shared__ float Ls[16 * 128];

    const int tid = threadIdx.x;
    const int lane = tid & 63, w = tid >> 6;
    const int row0 = blockIdx.y * 128, col0 = blockIdx.x * 128;
    const int wr = (w >> 1) * 64, wc = (w & 1) * 64;

    // staging decode (per lane, constant across K-loop)
    const int s_lc = (lane & 7) ^ ((lane >> 3) & 7);
    const int s_rb = 2 * (lane >> 3) + (s_lc >> 2);   // row within 16-row group
    const int s_c8 = (s_lc & 3) * 8;                  // k element offset

    f32x4 acc[4][4];
    #pragma unroll
    for (int i = 0; i < 4; ++i)
        #pragma unroll
        for (int j = 0; j < 4; ++j)
            acc[i][j] = (f32x4){0.f, 0.f, 0.f, 0.f};

    const int arow = wr + (lane & 15);
    const int chunk = lane >> 4;

    for (int k0 = 0; k0 < K; k0 += 32) {
        // ---- stage: each wave issues 2 calls per tile buffer ----
        #pragma unroll
        for (int qq = 0; qq < 2; ++qq) {
            const int q = 2 * w + qq;
            const int r = 16 * q + s_rb;
            const __hip_bfloat16* gA = Ah + (size_t)(row0 + r) * K + k0 + s_c8;
            __builtin_amdgcn_global_load_lds(
                (const __attribute__((address_space(1))) void*)gA,
                (__attribute__((address_space(3))) void*)(As + q * 512), 16, 0, 0);
            const __hip_bfloat16* gB = Bh + (size_t)(col0 + r) * K + k0 + s_c8;
            __builtin_amdgcn_global_load_lds(
                (const __attribute__((address_space(1))) void*)gB,
                (__attribute__((address_space(3))) void*)(Bs + q * 512), 16, 0, 0);
            if constexpr (SPLIT) {
                const __hip_bfloat16* gAl = Al + (size_t)(row0 + r) * K + k0 + s_c8;
                __builtin_amdgcn_global_load_lds(
                    (const __attribute__((address_space(1))) void*)gAl,
                    (__attribute__((address_space(3))) void*)(As + TILE + q * 512), 16, 0, 0);
                const __hip_bfloat16* gBl = Bl + (size_t)(col0 + r) * K + k0 + s_c8;
                __builtin_amdgcn_global_load_lds(
                    (const __attribute__((address_space(1))) void*)gBl,
                    (__attribute__((address_space(3))) void*)(Bs + TILE + q * 512), 16, 0, 0);
            }
        }
        __syncthreads();

        // ---- fragments + MFMA ----
        const char* ab = (const char*)As;
        const char* bb = (const char*)Bs;
        bf16x8 a_h[4], b_h[4], a_l[4], b_l[4];
        #pragma unroll
        for (int mi = 0; mi < 4; ++mi) {
            int off = sw_off(arow + mi * 16, chunk);
            a_h[mi] = *(const bf16x8*)(ab + off);
            if constexpr (SPLIT) a_l[mi] = *(const bf16x8*)(ab + 2 * TILE + off);
        }
        #pragma unroll
        for (int nj = 0; nj < 4; ++nj) {
            int off = sw_off(wc + nj * 16 + (lane & 15), chunk);
            b_h[nj] = *(const bf16x8*)(bb + off);
            if constexpr (SPLIT) b_l[nj] = *(const bf16x8*)(bb + 2 * TILE + off);
        }
        #pragma unroll
        for (int mi = 0; mi < 4; ++mi)
            #pragma unroll
            for (int nj = 0; nj < 4; ++nj) {
                acc[mi][nj] = __builtin_amdgcn_mfma_f32_16x16x32_bf16(a_h[mi], b_h[nj], acc[mi][nj], 0, 0, 0);
                if constexpr (SPLIT) {
                    acc[mi][nj] = __builtin_amdgcn_mfma_f32_16x16x32_bf16(a_h[mi], b_l[nj], acc[mi][nj], 0, 0, 0);
                    acc[mi][nj] = __builtin_amdgcn_mfma_f32_16x16x32_bf16(a_l[mi], b_h[nj], acc[mi][nj], 0, 0, 0);
                }
            }
        __syncthreads();
    }

    // ---- epilogue: bias + LORA_SCALE * (t @ lb) ----
    {
        int r = tid >> 1, j0 = (tid & 1) * 8;
        const float4* src = (const float4*)(t + (size_t)(row0 + r) * RANK + j0);
        float4* dst = (float4*)(Ts + r * 16 + j0);
        dst[0] = src[0]; dst[1] = src[1];
        int rr = tid >> 4, c0 = (tid & 15) * 8;
        const float4* lsrc = (const float4*)(lb + (size_t)rr * N + col0 + c0);
        float4* ldst = (float4*)(Ls + rr * 128 + c0);
        ldst[0] = lsrc[0]; ldst[1] = lsrc[1];
    }
    __syncthreads();
    #pragma unroll
    for (int mi = 0; mi < 4; ++mi)
        #pragma unroll
        for (int nj = 0; nj < 4; ++nj) {
            const int coll = wc + nj * 16 + (lane & 15);
            const float bv = bias[col0 + coll];
            #pragma unroll
            for (int rg = 0; rg < 4; ++rg) {
                const int rowl = wr + mi * 16 + (lane >> 4) * 4 + rg;
                float lsum = 0.f;
                #pragma unroll
                for (int rr = 0; rr < 16; ++rr)
                    lsum += Ts[rowl * 16 + rr] * Ls[rr * 128 + coll];
                C[(size_t)(row0 + rowl) * N + col0 + coll] = acc[mi][nj][rg] + bv + LORA_SCALE * lsum;
            }
        }
}

// ---------------- flash attention (fp32 vector), bf16 out ----------------
__global__ __launch_bounds__(256, 2)
void flash_attn_kernel(const float* __restrict__ qkv,
                       const float* __restrict__ scale_p,
                       const float* __restrict__ zp_p,
                       __hip_bfloat16* __restrict__ outb) {
    const int qt = (gridDim.x - 1) - blockIdx.x;   // heavy tiles dispatch first
    const int h  = blockIdx.y;
    const int b  = blockIdx.z;
    const int tid = threadIdx.x;
    const int tx = tid & 15, ty = tid >> 4;
    const float scale = scale_p[0];
    const float zp    = zp_p[0];

    __shared__ float Qs[64][PAD];
    __shared__ float Ks[64][PAD];
    __shared__ float Vt[64][PAD];
    __shared__ float Ps[64][PAD];
    __shared__ float m_sh[64], l_sh[64], alpha_sh[64];
    __shared__ float red[64][4];

    const float* base = qkv + (size_t)b * TSEQ * C3;

    #pragma unroll
    for (int r = 0; r < 4; ++r) {
        int j = r * 256 + tid;
        int row = j >> 4;
        int d4  = (j & 15) * 4;
        const float4 v = *(const float4*)(base + (size_t)(qt * 64 + row) * C3 + h * 64 + d4);
        Qs[row][d4 + 0] = v.x * 0.125f;
        Qs[row][d4 + 1] = v.y * 0.125f;
        Qs[row][d4 + 2] = v.z * 0.125f;
        Qs[row][d4 + 3] = v.w * 0.125f;
    }
    if (tid < 64) { m_sh[tid] = -INFINITY; l_sh[tid] = 0.0f; }

    float o[4][4] = {};

    for (int kt = 0; kt <= qt; ++kt) {
        __syncthreads();
        #pragma unroll
        for (int r = 0; r < 4; ++r) {
            int j = r * 256 + tid;
            int row = j >> 4;
            int d4  = (j & 15) * 4;
            const float4 kv = *(const float4*)(base + (size_t)(kt * 64 + row) * C3 + N_EMBD + h * 64 + d4);
            Ks[row][d4 + 0] = fake_quant(kv.x, scale, zp);
            Ks[row][d4 + 1] = fake_quant(kv.y, scale, zp);
            Ks[row][d4 + 2] = fake_quant(kv.z, scale, zp);
            Ks[row][d4 + 3] = fake_quant(kv.w, scale, zp);
            const float4 vv = *(const float4*)(base + (size_t)(kt * 64 + row) * C3 + 2 * N_EMBD + h * 64 + d4);
            Vt[d4 + 0][row] = fake_quant(vv.x, scale, zp);
            Vt[d4 + 1][row] = fake_quant(vv.y, scale, zp);
            Vt[d4 + 2][row] = fake_quant(vv.z, scale, zp);
            Vt[d4 + 3][row] = fake_quant(vv.w, scale, zp);
        }
        __syncthreads();

        float s[4][4] = {};
        for (int d0 = 0; d0 < 64; d0 += 4) {
            float4 a4[4], b4[4];
            #pragma unroll
            for (int i = 0; i < 4; ++i) a4[i] = *(const float4*)&Qs[ty + 16 * i][d0];
            #pragma unroll
            for (int j = 0; j < 4; ++j) b4[j] = *(const float4*)&Ks[tx + 16 * j][d0];
            #pragma unroll
            for (int i = 0; i < 4; ++i)
                #pragma unroll
                for (int j = 0; j < 4; ++j)
                    s[i][j] += a4[i].x * b4[j].x + a4[i].y * b4[j].y
                             + a4[i].z * b4[j].z + a4[i].w * b4[j].w;
        }
        const bool diag = (kt == qt);
        #pragma unroll
        for (int i = 0; i < 4; ++i)
            #pragma unroll
            for (int j = 0; j < 4; ++j) {
                float v = s[i][j];
                if (diag && (tx + 16 * j > ty + 16 * i)) v = -INFINITY;
                Ps[ty + 16 * i][tx + 16 * j] = v;
            }
        __syncthreads();

        const int r  = tid >> 2;
        const int q4 = tid & 3;
        float lm = -INFINITY;
        for (int k = q4 * 16; k < q4 * 16 + 16; ++k) lm = fmaxf(lm, Ps[r][k]);
        red[r][q4] = lm;
        __syncthreads();
        if (tid < 64) {
            float tm = fmaxf(fmaxf(red[tid][0], red[tid][1]),
                             fmaxf(red[tid][2], red[tid][3]));
            float mo = m_sh[tid];
            float mn = fmaxf(mo, tm);
            m_sh[tid] = mn;
            alpha_sh[tid] = __expf(mo - mn);
        }
        __syncthreads();
        float ls = 0.0f;
        {
            const float mn = m_sh[r];
            for (int k = q4 * 16; k < q4 * 16 + 16; ++k) {
                float p = __expf(Ps[r][k] - mn);
                Ps[r][k] = p;
                ls += p;
            }
        }
        red[r][q4] = ls;
        __syncthreads();
        if (tid < 64)
            l_sh[tid] = alpha_sh[tid] * l_sh[tid]
                      + red[tid][0] + red[tid][1] + red[tid][2] + red[tid][3];

        float al[4];
        #pragma unroll
        for (int i = 0; i < 4; ++i) al[i] = alpha_sh[ty + 16 * i];
        #pragma unroll
        for (int i = 0; i < 4; ++i)
            #pragma unroll
            for (int j = 0; j < 4; ++j) o[i][j] *= al[i];

        for (int k0 = 0; k0 < 64; k0 += 4) {
            float4 a4[4], b4[4];
            #pragma unroll
            for (int i = 0; i < 4; ++i) a4[i] = *(const float4*)&Ps[ty + 16 * i][k0];
            #pragma unroll
            for (int j = 0; j < 4; ++j) b4[j] = *(const float4*)&Vt[tx + 16 * j][k0];
            #pragma unroll
            for (int i = 0; i < 4; ++i)
                #pragma unroll
                for (int j = 0; j < 4; ++j)
                    o[i][j] += a4[i].x * b4[j].x + a4[i].y * b4[j].y
                             + a4[i].z * b4[j].z + a4[i].w * b4[j].w;
        }
    }
    __syncthreads();

    #pragma unroll
    for (int i = 0; i < 4; ++i) {
        const int q = ty + 16 * i;
        const float inv_l = 1.0f / l_sh[q];
        #pragma unroll
        for (int j = 0; j < 4; ++j) {
            const int d = tx + 16 * j;
            outb[((size_t)b * TSEQ + qt * 64 + q) * N_EMBD + h * 64 + d] =
                __float2bfloat16(o[i][j] * inv_l);
        }
    }
}

extern "C" void kernel_launch(void* const* d_in, const int* in_sizes, int n_in,
                              void* d_out, int out_size, void* d_ws, size_t ws_size,
                              hipStream_t stream) {
    const float* x        = (const float*)d_in[0];
    const float* w_attn   = (const float*)d_in[1];
    const float* b_attn   = (const float*)d_in[2];
    const float* la_attn  = (const float*)d_in[3];
    const float* lb_attn  = (const float*)d_in[4];
    const float* w_proj   = (const float*)d_in[5];
    const float* b_proj   = (const float*)d_in[6];
    const float* la_proj  = (const float*)d_in[7];
    const float* lb_proj  = (const float*)d_in[8];
    const float* kv_scale = (const float*)d_in[9];
    const float* kv_zp    = (const float*)d_in[10];
    float* out = (float*)d_out;

    char* ws = (char*)d_ws;
    float* qkv            = (float*)ws;                       ws += (size_t)M_TOTAL * C3 * 4;      // 50.3 MB
    float* t_attn         = (float*)ws;                       ws += (size_t)M_TOTAL * RANK * 4;
    float* t_proj         = (float*)ws;                       ws += (size_t)M_TOTAL * RANK * 4;
    __hip_bfloat16* aob   = (__hip_bfloat16*)ws;              ws += (size_t)M_TOTAL * N_EMBD * 2;  // attn out bf16
    __hip_bfloat16* x_hi  = (__hip_bfloat16*)ws;              ws += (size_t)M_TOTAL * N_EMBD * 2;
    __hip_bfloat16* x_lo  = (__hip_bfloat16*)ws;              ws += (size_t)M_TOTAL * N_EMBD * 2;
    __hip_bfloat16* wqT_h = (__hip_bfloat16*)ws;              ws += (size_t)C3 * N_EMBD * 2;
    __hip_bfloat16* wqT_l = (__hip_bfloat16*)ws;              ws += (size_t)C3 * N_EMBD * 2;
    __hip_bfloat16* wpT   = (__hip_bfloat16*)ws;              ws += (size_t)N_EMBD * N_EMBD * 2;

    cvt_split_kernel<<<dim3(M_TOTAL * N_EMBD / 4 / 256), 256, 0, stream>>>(
        x, x_hi, x_lo, M_TOTAL * N_EMBD / 4);
    transpose_split_kernel<<<dim3(C3 / 32, N_EMBD / 32), 256, 0, stream>>>(
        w_attn, wqT_h, wqT_l, N_EMBD, C3);
    transpose_split_kernel<<<dim3(N_EMBD / 32, N_EMBD / 32), 256, 0, stream>>>(
        w_proj, wpT, nullptr, N_EMBD, N_EMBD);
    lora_t_kernel<<<dim3(M_TOTAL / 16), 256, 0, stream>>>(x, la_attn, t_attn, N_EMBD);

    gemm_mfma_kernel<true><<<dim3(C3 / 128, M_TOTAL / 128), 256, 0, stream>>>(
        x_hi, x_lo, wqT_h, wqT_l, b_attn, t_attn, lb_attn, qkv, M_TOTAL, C3, N_EMBD);

    flash_attn_kernel<<<dim3(TSEQ / 64, N_HEAD, BATCH), 256, 0, stream>>>(
        qkv, kv_scale, kv_zp, aob);

    lora_t_bf16_kernel<<<dim3(M_TOTAL / 16), 256, 0, stream>>>(aob, la_proj, t_proj, N_EMBD);

    gemm_mfma_kernel<false><<<dim3(N_EMBD / 128, M_TOTAL / 128), 256, 0, stream>>>(
        aob, nullptr, wpT, nullptr, b_proj, t_proj, lb_proj, out, M_TOTAL, N_EMBD, N_EMBD);
}

// Round 4
// 406.204 us; speedup vs baseline: 12.3028x; 3.0834x over previous
//
#include <hip/hip_runtime.h>
#include <hip/hip_bf16.h>
#include <math.h>

#define N_EMBD   1024
#define N_HEAD   16
#define HEAD_DIM 64
#define BATCH    2
#define TSEQ     2048
#define RANK     16
#define LORA_SCALE 2.0f
#define M_TOTAL  (BATCH * TSEQ)   // 4096
#define C3       (3 * N_EMBD)     // 3072

typedef unsigned short ushort_t;
typedef __attribute__((ext_vector_type(8))) short bf16x8;
typedef __attribute__((ext_vector_type(4))) float f32x4;

__device__ __forceinline__ float fake_quant(float x, float scale, float zp) {
    float q = rintf(x / scale + zp);
    q = fminf(fmaxf(q, 0.0f), 255.0f);
    return (q - zp) * scale;
}

__device__ __forceinline__ ushort_t bf16bits(float f) {
    union { __hip_bfloat16 h; ushort_t u; } c;
    c.h = __float2bfloat16(f);
    return c.u;
}

__device__ __forceinline__ float bfraw2f(ushort_t u) {
    union { unsigned int i; float f; } c; c.i = ((unsigned int)u) << 16; return c.f;
}

// ---------------- conversion kernels ----------------
__global__ void cvt_split_kernel(const float* __restrict__ in,
                                 __hip_bfloat16* __restrict__ hi,
                                 __hip_bfloat16* __restrict__ lo, int n4) {
    int i = blockIdx.x * 256 + threadIdx.x;
    if (i >= n4) return;
    float4 v = ((const float4*)in)[i];
    float vs[4] = {v.x, v.y, v.z, v.w};
    #pragma unroll
    for (int k = 0; k < 4; ++k) {
        __hip_bfloat16 h = __float2bfloat16(vs[k]);
        hi[i * 4 + k] = h;
        lo[i * 4 + k] = __float2bfloat16(vs[k] - __bfloat162float(h));
    }
}

__global__ void transpose_split_kernel(const float* __restrict__ in,
                                       __hip_bfloat16* __restrict__ hiT,
                                       __hip_bfloat16* __restrict__ loT,
                                       int R, int C) {
    __shared__ float tl[32][33];
    const int c0 = blockIdx.x * 32, r0 = blockIdx.y * 32;
    const int tx = threadIdx.x & 31, ty = threadIdx.x >> 5;
    for (int i = ty; i < 32; i += 8)
        tl[i][tx] = in[(size_t)(r0 + i) * C + c0 + tx];
    __syncthreads();
    for (int i = ty; i < 32; i += 8) {
        float v = tl[tx][i];
        __hip_bfloat16 h = __float2bfloat16(v);
        size_t o = (size_t)(c0 + i) * R + r0 + tx;
        hiT[o] = h;
        if (loT) loT[o] = __float2bfloat16(v - __bfloat162float(h));
    }
}

// ---------------- K/V fake-quant pre-pass ----------------
// Kq[bh][T][64] bf16
__global__ void kquant_kernel(const float* __restrict__ qkv,
                              const float* __restrict__ sp, const float* __restrict__ zp,
                              ushort_t* __restrict__ Kq) {
    const float scale = sp[0], z = zp[0];
    int i = blockIdx.x * 256 + threadIdx.x;        // over 32*2048*16 float4-groups
    int d4 = i & 15, t = (i >> 4) & 2047, bh = i >> 15;
    int b = bh >> 4, h = bh & 15;
    const float4 v = *(const float4*)(qkv + ((size_t)b * TSEQ + t) * C3 + N_EMBD + h * 64 + d4 * 4);
    ushort4 u;
    u.x = bf16bits(fake_quant(v.x, scale, z));
    u.y = bf16bits(fake_quant(v.y, scale, z));
    u.z = bf16bits(fake_quant(v.z, scale, z));
    u.w = bf16bits(fake_quant(v.w, scale, z));
    *(ushort4*)(Kq + ((size_t)bh * TSEQ + t) * 64 + d4 * 4) = u;
}

// Vt[bh][64 d][T] bf16 (transposed)
__global__ void vtquant_kernel(const float* __restrict__ qkv,
                               const float* __restrict__ sp, const float* __restrict__ zp,
                               ushort_t* __restrict__ Vt) {
    __shared__ ushort_t tl[64][72];
    const int bh = blockIdx.x & 31, tt = blockIdx.x >> 5;
    const int b = bh >> 4, h = bh & 15;
    const float scale = sp[0], z = zp[0];
    const int tid = threadIdx.x;
    #pragma unroll
    for (int i = 0; i < 4; ++i) {
        int t = 16 * i + (tid >> 4), d0 = (tid & 15) * 4;
        float4 v = *(const float4*)(qkv + ((size_t)b * TSEQ + tt * 64 + t) * C3 + 2 * N_EMBD + h * 64 + d0);
        tl[d0 + 0][t] = bf16bits(fake_quant(v.x, scale, z));
        tl[d0 + 1][t] = bf16bits(fake_quant(v.y, scale, z));
        tl[d0 + 2][t] = bf16bits(fake_quant(v.z, scale, z));
        tl[d0 + 3][t] = bf16bits(fake_quant(v.w, scale, z));
    }
    __syncthreads();
    const int d = tid >> 2, t0 = (tid & 3) * 16;
    unsigned int wbuf[8];
    #pragma unroll
    for (int j = 0; j < 8; ++j)
        wbuf[j] = (unsigned int)tl[d][t0 + 2 * j] | ((unsigned int)tl[d][t0 + 2 * j + 1] << 16);
    ushort_t* dst = Vt + ((size_t)bh * 64 + d) * TSEQ + tt * 64 + t0;
    *(uint4*)dst       = make_uint4(wbuf[0], wbuf[1], wbuf[2], wbuf[3]);
    *(uint4*)(dst + 8) = make_uint4(wbuf[4], wbuf[5], wbuf[6], wbuf[7]);
}

// ---------------- LoRA rank-16 projection, 4-way K-split ----------------
__global__ void lora_t_part_kernel(const float* __restrict__ x,
                                   const float* __restrict__ la,
                                   float* __restrict__ tpart, int K) {
    __shared__ float Xs[16][64];
    const int tid = threadIdx.x;
    const int ty = tid >> 4, tx = tid & 15;
    const int row0 = blockIdx.x * 16;
    const int kbase = blockIdx.y * 256;
    float acc = 0.0f;
    for (int k0 = kbase; k0 < kbase + 256; k0 += 64) {
        int rr = tid >> 4, kk = (tid & 15) * 4;
        float4 v = *(const float4*)(x + (size_t)(row0 + rr) * K + k0 + kk);
        Xs[rr][kk] = v.x; Xs[rr][kk + 1] = v.y; Xs[rr][kk + 2] = v.z; Xs[rr][kk + 3] = v.w;
        __syncthreads();
        for (int k = 0; k < 64; ++k)
            acc += Xs[ty][k] * la[(size_t)(k0 + k) * RANK + tx];
        __syncthreads();
    }
    tpart[((size_t)blockIdx.y * M_TOTAL + row0 + ty) * RANK + tx] = acc;
}

__global__ void lora_t_part_bf16_kernel(const ushort_t* __restrict__ x,
                                        const float* __restrict__ la,
                                        float* __restrict__ tpart, int K) {
    __shared__ float Xs[16][64];
    const int tid = threadIdx.x;
    const int ty = tid >> 4, tx = tid & 15;
    const int row0 = blockIdx.x * 16;
    const int kbase = blockIdx.y * 256;
    float acc = 0.0f;
    for (int k0 = kbase; k0 < kbase + 256; k0 += 64) {
        int rr = tid >> 4, kk = (tid & 15) * 4;
        const ushort4 u = *(const ushort4*)(x + (size_t)(row0 + rr) * K + k0 + kk);
        Xs[rr][kk] = bfraw2f(u.x); Xs[rr][kk + 1] = bfraw2f(u.y);
        Xs[rr][kk + 2] = bfraw2f(u.z); Xs[rr][kk + 3] = bfraw2f(u.w);
        __syncthreads();
        for (int k = 0; k < 64; ++k)
            acc += Xs[ty][k] * la[(size_t)(k0 + k) * RANK + tx];
        __syncthreads();
    }
    tpart[((size_t)blockIdx.y * M_TOTAL + row0 + ty) * RANK + tx] = acc;
}

// ---------------- MFMA GEMM (128x128 tile, BK=32) ----------------
__device__ __forceinline__ int sw_off(int r, int c) {
    return ((r >> 1) << 7) + (((((r & 1) << 2) | c) ^ ((r >> 1) & 7)) << 4);
}

template <bool SPLIT>
__global__ __launch_bounds__(256)
void gemm_mfma_kernel(const __hip_bfloat16* __restrict__ Ah,
                      const __hip_bfloat16* __restrict__ Al,
                      const __hip_bfloat16* __restrict__ Bh,
                      const __hip_bfloat16* __restrict__ Bl,
                      const float* __restrict__ bias,
                      const float* __restrict__ tpart,
                      const float* __restrict__ lb,
                      float* __restrict__ C,
                      int M, int N, int K) {
    constexpr int TILE = 128 * 32;
    __shared__ __hip_bfloat16 As[SPLIT ? 2 * TILE : TILE];
    __shared__ __hip_bfloat16 Bs[SPLIT ? 2 * TILE : TILE];
    __shared__ float Ts[128 * 16];
    __shared__ float Ls[16 * 128];

    const int tid = threadIdx.x;
    const int lane = tid & 63, w = tid >> 6;
    const int row0 = blockIdx.y * 128, col0 = blockIdx.x * 128;
    const int wr = (w >> 1) * 64, wc = (w & 1) * 64;

    const int s_lc = (lane & 7) ^ ((lane >> 3) & 7);
    const int s_rb = 2 * (lane >> 3) + (s_lc >> 2);
    const int s_c8 = (s_lc & 3) * 8;

    f32x4 acc[4][4];
    #pragma unroll
    for (int i = 0; i < 4; ++i)
        #pragma unroll
        for (int j = 0; j < 4; ++j)
            acc[i][j] = (f32x4){0.f, 0.f, 0.f, 0.f};

    const int arow = wr + (lane & 15);
    const int chunk = lane >> 4;

    for (int k0 = 0; k0 < K; k0 += 32) {
        #pragma unroll
        for (int qq = 0; qq < 2; ++qq) {
            const int q = 2 * w + qq;
            const int r = 16 * q + s_rb;
            const __hip_bfloat16* gA = Ah + (size_t)(row0 + r) * K + k0 + s_c8;
            __builtin_amdgcn_global_load_lds(
                (const __attribute__((address_space(1))) void*)gA,
                (__attribute__((address_space(3))) void*)(As + q * 512), 16, 0, 0);
            const __hip_bfloat16* gB = Bh + (size_t)(col0 + r) * K + k0 + s_c8;
            __builtin_amdgcn_global_load_lds(
                (const __attribute__((address_space(1))) void*)gB,
                (__attribute__((address_space(3))) void*)(Bs + q * 512), 16, 0, 0);
            if constexpr (SPLIT) {
                const __hip_bfloat16* gAl = Al + (size_t)(row0 + r) * K + k0 + s_c8;
                __builtin_amdgcn_global_load_lds(
                    (const __attribute__((address_space(1))) void*)gAl,
                    (__attribute__((address_space(3))) void*)(As + TILE + q * 512), 16, 0, 0);
                const __hip_bfloat16* gBl = Bl + (size_t)(col0 + r) * K + k0 + s_c8;
                __builtin_amdgcn_global_load_lds(
                    (const __attribute__((address_space(1))) void*)gBl,
                    (__attribute__((address_space(3))) void*)(Bs + TILE + q * 512), 16, 0, 0);
            }
        }
        __syncthreads();

        const char* ab = (const char*)As;
        const char* bb = (const char*)Bs;
        bf16x8 a_h[4], b_h[4], a_l[4], b_l[4];
        #pragma unroll
        for (int mi = 0; mi < 4; ++mi) {
            int off = sw_off(arow + mi * 16, chunk);
            a_h[mi] = *(const bf16x8*)(ab + off);
            if constexpr (SPLIT) a_l[mi] = *(const bf16x8*)(ab + 2 * TILE + off);
        }
        #pragma unroll
        for (int nj = 0; nj < 4; ++nj) {
            int off = sw_off(wc + nj * 16 + (lane & 15), chunk);
            b_h[nj] = *(const bf16x8*)(bb + off);
            if constexpr (SPLIT) b_l[nj] = *(const bf16x8*)(bb + 2 * TILE + off);
        }
        #pragma unroll
        for (int mi = 0; mi < 4; ++mi)
            #pragma unroll
            for (int nj = 0; nj < 4; ++nj) {
                acc[mi][nj] = __builtin_amdgcn_mfma_f32_16x16x32_bf16(a_h[mi], b_h[nj], acc[mi][nj], 0, 0, 0);
                if constexpr (SPLIT) {
                    acc[mi][nj] = __builtin_amdgcn_mfma_f32_16x16x32_bf16(a_h[mi], b_l[nj], acc[mi][nj], 0, 0, 0);
                    acc[mi][nj] = __builtin_amdgcn_mfma_f32_16x16x32_bf16(a_l[mi], b_h[nj], acc[mi][nj], 0, 0, 0);
                }
            }
        __syncthreads();
    }

    // epilogue: bias + LORA_SCALE * ((sum of tparts) @ lb)
    {
        int r = tid >> 1, j0 = (tid & 1) * 8;
        float4 t0 = {0, 0, 0, 0}, t1 = {0, 0, 0, 0};
        #pragma unroll
        for (int c = 0; c < 4; ++c) {
            const float* src = tpart + ((size_t)c * M_TOTAL + row0 + r) * RANK + j0;
            float4 s0 = *(const float4*)src;
            float4 s1 = *(const float4*)(src + 4);
            t0.x += s0.x; t0.y += s0.y; t0.z += s0.z; t0.w += s0.w;
            t1.x += s1.x; t1.y += s1.y; t1.z += s1.z; t1.w += s1.w;
        }
        *(float4*)(Ts + r * 16 + j0)     = t0;
        *(float4*)(Ts + r * 16 + j0 + 4) = t1;
        int rr = tid >> 4, c0 = (tid & 15) * 8;
        const float4* lsrc = (const float4*)(lb + (size_t)rr * N + col0 + c0);
        float4* ldst = (float4*)(Ls + rr * 128 + c0);
        ldst[0] = lsrc[0]; ldst[1] = lsrc[1];
    }
    __syncthreads();
    #pragma unroll
    for (int mi = 0; mi < 4; ++mi)
        #pragma unroll
        for (int nj = 0; nj < 4; ++nj) {
            const int coll = wc + nj * 16 + (lane & 15);
            const float bv = bias[col0 + coll];
            #pragma unroll
            for (int rg = 0; rg < 4; ++rg) {
                const int rowl = wr + mi * 16 + (lane >> 4) * 4 + rg;
                float lsum = 0.f;
                #pragma unroll
                for (int rr = 0; rr < 16; ++rr)
                    lsum += Ts[rowl * 16 + rr] * Ls[rr * 128 + coll];
                C[(size_t)(row0 + rowl) * N + col0 + coll] = acc[mi][nj][rg] + bv + LORA_SCALE * lsum;
            }
        }
}

// ---------------- MFMA flash attention ----------------
// 64x64 tiles, 4 waves x 16 q-rows, XOR-swizzled 128B LDS rows.
__global__ __launch_bounds__(256)
void mfma_attn_kernel(const float* __restrict__ qkv,
                      const ushort_t* __restrict__ Kq,   // [bh][T][64]
                      const ushort_t* __restrict__ Vtq,  // [bh][64][T]
                      ushort_t* __restrict__ outb) {     // [B][T][1024] bf16
    const int bx = blockIdx.x;
    const int bh = bx & 31;
    const int qt = 31 - (bx >> 5);                 // heavy q-tiles dispatch first
    const int b = bh >> 4, h = bh & 15;
    const int tid = threadIdx.x;
    const int lane = tid & 63, w = tid >> 6;
    const int m16 = lane & 15, qc = lane >> 4;
    const int m7 = m16 & 7;

    __shared__ ushort_t Qs[4096];
    __shared__ ushort_t Ks[4096];
    __shared__ ushort_t Vs[4096];
    __shared__ ushort_t Ps[4096];

    // ---- stage Q once (fp32 -> bf16, fold 1/sqrt(64)) ----
    {
        const int row = tid >> 2;
        const int d0 = (tid & 3) * 16;
        const float* src = qkv + ((size_t)b * TSEQ + qt * 64 + row) * C3 + h * 64 + d0;
        unsigned int wbuf[8];
        #pragma unroll
        for (int j = 0; j < 4; ++j) {
            float4 v = *(const float4*)(src + 4 * j);
            wbuf[2 * j]     = (unsigned int)bf16bits(v.x * 0.125f) | ((unsigned int)bf16bits(v.y * 0.125f) << 16);
            wbuf[2 * j + 1] = (unsigned int)bf16bits(v.z * 0.125f) | ((unsigned int)bf16bits(v.w * 0.125f) << 16);
        }
        unsigned int* qw = (unsigned int*)Qs;
        const int ga = (tid & 3) * 2;
        *(uint4*)&qw[row * 32 + ((ga ^ (row & 7)) << 2)]       = make_uint4(wbuf[0], wbuf[1], wbuf[2], wbuf[3]);
        *(uint4*)&qw[row * 32 + (((ga + 1) ^ (row & 7)) << 2)] = make_uint4(wbuf[4], wbuf[5], wbuf[6], wbuf[7]);
    }
    __syncthreads();

    // hoist Q A-fragments (reused every kt)
    bf16x8 a_q[2];
    {
        const int row = 16 * w + m16;
        #pragma unroll
        for (int c = 0; c < 2; ++c) {
            const int g = qc + 4 * c;
            a_q[c] = *(const bf16x8*)((const char*)Qs + row * 128 + ((g ^ m7) << 4));
        }
    }

    float m_st[4], l_st[4];
    f32x4 o_acc[4];
    #pragma unroll
    for (int r = 0; r < 4; ++r) { m_st[r] = -INFINITY; l_st[r] = 0.0f; }
    #pragma unroll
    for (int dj = 0; dj < 4; ++dj) o_acc[dj] = (f32x4){0.f, 0.f, 0.f, 0.f};

    const ushort_t* Kg = Kq + (size_t)bh * TSEQ * 64;
    const ushort_t* Vg = Vtq + (size_t)bh * 64 * TSEQ;
    const int s_g = (lane & 7) ^ ((lane >> 3) & 7);   // staging granule decode
    const int s_r = lane >> 3;

    for (int kt = 0; kt <= qt; ++kt) {
        __syncthreads();   // previous tile's readers done
        #pragma unroll
        for (int pp = 0; pp < 2; ++pp) {
            const int p = 2 * w + pp;
            const ushort_t* gk = Kg + ((size_t)(kt * 64 + 8 * p + s_r)) * 64 + s_g * 8;
            __builtin_amdgcn_global_load_lds(
                (const __attribute__((address_space(1))) void*)gk,
                (__attribute__((address_space(3))) void*)(Ks + p * 512), 16, 0, 0);
            const ushort_t* gv = Vg + ((size_t)(8 * p + s_r)) * TSEQ + kt * 64 + s_g * 8;
            __builtin_amdgcn_global_load_lds(
                (const __attribute__((address_space(1))) void*)gv,
                (__attribute__((address_space(3))) void*)(Vs + p * 512), 16, 0, 0);
        }
        __syncthreads();   // staging complete

        const bool diag = (kt == qt);
        const int nj_hi = diag ? (w + 1) : 4;

        // ---- S = Q @ K^T ----
        f32x4 s[4];
        #pragma unroll
        for (int nj = 0; nj < 4; ++nj) s[nj] = (f32x4){0.f, 0.f, 0.f, 0.f};
        #pragma unroll
        for (int c = 0; c < 2; ++c) {
            #pragma unroll
            for (int nj = 0; nj < 4; ++nj) {
                if (nj < nj_hi) {
                    const int row = 16 * nj + m16;
                    const int g = qc + 4 * c;
                    bf16x8 bk = *(const bf16x8*)((const char*)Ks + row * 128 + ((g ^ m7) << 4));
                    s[nj] = __builtin_amdgcn_mfma_f32_16x16x32_bf16(a_q[c], bk, s[nj], 0, 0, 0);
                }
            }
        }

        // ---- online softmax (state in registers, 16-lane shfl reductions) ----
        float alpha[4], p_[4][4];
        #pragma unroll
        for (int reg = 0; reg < 4; ++reg) {
            const int qrow = 16 * w + 4 * qc + reg;   // in-block q row
            float sv[4];
            float rm = -INFINITY;
            #pragma unroll
            for (int nj = 0; nj < 4; ++nj) {
                float v = s[nj][reg];
                if (diag && (m16 + 16 * nj > qrow)) v = -INFINITY;
                sv[nj] = v;
                rm = fmaxf(rm, v);
            }
            #pragma unroll
            for (int off = 1; off < 16; off <<= 1)
                rm = fmaxf(rm, __shfl_xor(rm, off, 16));
            const float mo = m_st[reg];
            const float mn = fmaxf(mo, rm);
            const float al = __expf(mo - mn);
            float rs = 0.f;
            #pragma unroll
            for (int nj = 0; nj < 4; ++nj) {
                float pv = __expf(sv[nj] - mn);
                p_[reg][nj] = pv;
                rs += pv;
            }
            #pragma unroll
            for (int off = 1; off < 16; off <<= 1)
                rs += __shfl_xor(rs, off, 16);
            l_st[reg] = al * l_st[reg] + rs;
            m_st[reg] = mn;
            alpha[reg] = al;
        }

        // ---- P -> LDS (bf16, same-wave round trip, no barrier) ----
        #pragma unroll
        for (int reg = 0; reg < 4; ++reg) {
            const int row = 16 * w + 4 * qc + reg;
            const int r7 = row & 7;
            #pragma unroll
            for (int nj = 0; nj < 4; ++nj) {
                const int k = m16 + 16 * nj;
                Ps[row * 64 + (((k >> 3) ^ r7) << 3) + (k & 7)] = bf16bits(p_[reg][nj]);
            }
        }

        // ---- rescale O, then O += P @ V ----
        #pragma unroll
        for (int dj = 0; dj < 4; ++dj)
            #pragma unroll
            for (int reg = 0; reg < 4; ++reg)
                o_acc[dj][reg] *= alpha[reg];

        const int c_hi = diag ? (w >= 2 ? 2 : 1) : 2;
        #pragma unroll
        for (int c = 0; c < 2; ++c) {
            if (c < c_hi) {
                const int rowp = 16 * w + m16;
                const int g = qc + 4 * c;
                bf16x8 ap = *(const bf16x8*)((const char*)Ps + rowp * 128 + ((g ^ m7) << 4));
                #pragma unroll
                for (int dj = 0; dj < 4; ++dj) {
                    const int rowv = 16 * dj + m16;
                    bf16x8 bv = *(const bf16x8*)((const char*)Vs + rowv * 128 + ((g ^ m7) << 4));
                    o_acc[dj] = __builtin_amdgcn_mfma_f32_16x16x32_bf16(ap, bv, o_acc[dj], 0, 0, 0);
                }
            }
        }
    }

    // ---- epilogue: O / l -> bf16 ----
    #pragma unroll
    for (int reg = 0; reg < 4; ++reg) {
        const float inv = 1.0f / l_st[reg];
        const int q = qt * 64 + 16 * w + 4 * qc + reg;
        #pragma unroll
        for (int dj = 0; dj < 4; ++dj) {
            const int d = m16 + 16 * dj;
            outb[((size_t)b * TSEQ + q) * N_EMBD + h * 64 + d] = bf16bits(o_acc[dj][reg] * inv);
        }
    }
}

extern "C" void kernel_launch(void* const* d_in, const int* in_sizes, int n_in,
                              void* d_out, int out_size, void* d_ws, size_t ws_size,
                              hipStream_t stream) {
    const float* x        = (const float*)d_in[0];
    const float* w_attn   = (const float*)d_in[1];
    const float* b_attn   = (const float*)d_in[2];
    const float* la_attn  = (const float*)d_in[3];
    const float* lb_attn  = (const float*)d_in[4];
    const float* w_proj   = (const float*)d_in[5];
    const float* b_proj   = (const float*)d_in[6];
    const float* la_proj  = (const float*)d_in[7];
    const float* lb_proj  = (const float*)d_in[8];
    const float* kv_scale = (const float*)d_in[9];
    const float* kv_zp    = (const float*)d_in[10];
    float* out = (float*)d_out;

    char* ws = (char*)d_ws;
    float* qkv            = (float*)ws;          ws += (size_t)M_TOTAL * C3 * 4;
    float* t_attn_p       = (float*)ws;          ws += (size_t)4 * M_TOTAL * RANK * 4;
    float* t_proj_p       = (float*)ws;          ws += (size_t)4 * M_TOTAL * RANK * 4;
    ushort_t* aob         = (ushort_t*)ws;       ws += (size_t)M_TOTAL * N_EMBD * 2;
    __hip_bfloat16* x_hi  = (__hip_bfloat16*)ws; ws += (size_t)M_TOTAL * N_EMBD * 2;
    __hip_bfloat16* x_lo  = (__hip_bfloat16*)ws; ws += (size_t)M_TOTAL * N_EMBD * 2;
    __hip_bfloat16* wqT_h = (__hip_bfloat16*)ws; ws += (size_t)C3 * N_EMBD * 2;
    __hip_bfloat16* wqT_l = (__hip_bfloat16*)ws; ws += (size_t)C3 * N_EMBD * 2;
    __hip_bfloat16* wpT   = (__hip_bfloat16*)ws; ws += (size_t)N_EMBD * N_EMBD * 2;
    ushort_t* Kq          = (ushort_t*)ws;       ws += (size_t)32 * TSEQ * 64 * 2;
    ushort_t* Vtq         = (ushort_t*)ws;       ws += (size_t)32 * 64 * TSEQ * 2;

    cvt_split_kernel<<<dim3(M_TOTAL * N_EMBD / 4 / 256), 256, 0, stream>>>(
        x, x_hi, x_lo, M_TOTAL * N_EMBD / 4);
    transpose_split_kernel<<<dim3(C3 / 32, N_EMBD / 32), 256, 0, stream>>>(
        w_attn, wqT_h, wqT_l, N_EMBD, C3);
    transpose_split_kernel<<<dim3(N_EMBD / 32, N_EMBD / 32), 256, 0, stream>>>(
        w_proj, wpT, nullptr, N_EMBD, N_EMBD);
    lora_t_part_kernel<<<dim3(M_TOTAL / 16, 4), 256, 0, stream>>>(x, la_attn, t_attn_p, N_EMBD);

    gemm_mfma_kernel<true><<<dim3(C3 / 128, M_TOTAL / 128), 256, 0, stream>>>(
        x_hi, x_lo, wqT_h, wqT_l, b_attn, t_attn_p, lb_attn, qkv, M_TOTAL, C3, N_EMBD);

    kquant_kernel<<<dim3(32 * TSEQ * 16 / 256), 256, 0, stream>>>(qkv, kv_scale, kv_zp, Kq);
    vtquant_kernel<<<dim3(32 * (TSEQ / 64)), 256, 0, stream>>>(qkv, kv_scale, kv_zp, Vtq);

    mfma_attn_kernel<<<dim3(32 * 32), 256, 0, stream>>>(qkv, Kq, Vtq, aob);

    lora_t_part_bf16_kernel<<<dim3(M_TOTAL / 16, 4), 256, 0, stream>>>(aob, la_proj, t_proj_p, N_EMBD);

    gemm_mfma_kernel<false><<<dim3(N_EMBD / 128, M_TOTAL / 128), 256, 0, stream>>>(
        (const __hip_bfloat16*)aob, nullptr, wpT, nullptr, b_proj, t_proj_p, lb_proj, out,
        M_TOTAL, N_EMBD, N_EMBD);
}

// Round 5
// 382.345 us; speedup vs baseline: 13.0705x; 1.0624x over previous
//
#include <hip/hip_runtime.h>
#include <hip/hip_bf16.h>
#include <math.h>

#define N_EMBD   1024
#define N_HEAD   16
#define HEAD_DIM 64
#define BATCH    2
#define TSEQ     2048
#define RANK     16
#define LORA_SCALE 2.0f
#define M_TOTAL  (BATCH * TSEQ)   // 4096
#define C3       (3 * N_EMBD)     // 3072

typedef unsigned short ushort_t;
typedef __attribute__((ext_vector_type(8))) short bf16x8;
typedef __attribute__((ext_vector_type(4))) float f32x4;

__device__ __forceinline__ float fake_quant(float x, float scale, float zp) {
    float q = rintf(x / scale + zp);
    q = fminf(fmaxf(q, 0.0f), 255.0f);
    return (q - zp) * scale;
}

__device__ __forceinline__ ushort_t bf16bits(float f) {
    union { __hip_bfloat16 h; ushort_t u; } c;
    c.h = __float2bfloat16(f);
    return c.u;
}

__device__ __forceinline__ float bfraw2f(ushort_t u) {
    union { unsigned int i; float f; } c; c.i = ((unsigned int)u) << 16; return c.f;
}

// ---------------- conversion kernels ----------------
__global__ void cvt_split_kernel(const float* __restrict__ in,
                                 __hip_bfloat16* __restrict__ hi,
                                 __hip_bfloat16* __restrict__ lo, int n4) {
    int i = blockIdx.x * 256 + threadIdx.x;
    if (i >= n4) return;
    float4 v = ((const float4*)in)[i];
    float vs[4] = {v.x, v.y, v.z, v.w};
    #pragma unroll
    for (int k = 0; k < 4; ++k) {
        __hip_bfloat16 h = __float2bfloat16(vs[k]);
        hi[i * 4 + k] = h;
        lo[i * 4 + k] = __float2bfloat16(vs[k] - __bfloat162float(h));
    }
}

__global__ void transpose_split_kernel(const float* __restrict__ in,
                                       __hip_bfloat16* __restrict__ hiT,
                                       __hip_bfloat16* __restrict__ loT,
                                       int R, int C) {
    __shared__ float tl[32][33];
    const int c0 = blockIdx.x * 32, r0 = blockIdx.y * 32;
    const int tx = threadIdx.x & 31, ty = threadIdx.x >> 5;
    for (int i = ty; i < 32; i += 8)
        tl[i][tx] = in[(size_t)(r0 + i) * C + c0 + tx];
    __syncthreads();
    for (int i = ty; i < 32; i += 8) {
        float v = tl[tx][i];
        __hip_bfloat16 h = __float2bfloat16(v);
        size_t o = (size_t)(c0 + i) * R + r0 + tx;
        hiT[o] = h;
        if (loT) loT[o] = __float2bfloat16(v - __bfloat162float(h));
    }
}

// Vb[bh][t][d] -> Vt[bh][d][t]  (bf16 transpose, 64x64 tiles)
__global__ void vtrans_kernel(const ushort_t* __restrict__ Vb,
                              ushort_t* __restrict__ Vt) {
    __shared__ ushort_t tl[64][68];
    const int bh = blockIdx.x & 31, tt = blockIdx.x >> 5;
    const int tid = threadIdx.x;
    {
        const int t = tid >> 2, d0 = (tid & 3) * 16;
        const uint4 u = *(const uint4*)(Vb + ((size_t)bh * TSEQ + tt * 64 + t) * 64 + d0);
        *(uint4*)&tl[t][d0] = u;
        *(uint4*)&tl[t][d0 + 8] = *(const uint4*)(Vb + ((size_t)bh * TSEQ + tt * 64 + t) * 64 + d0 + 8);
    }
    __syncthreads();
    const int d = tid >> 2, t0 = (tid & 3) * 16;
    unsigned int wbuf[8];
    #pragma unroll
    for (int j = 0; j < 8; ++j)
        wbuf[j] = (unsigned int)tl[t0 + 2 * j][d] | ((unsigned int)tl[t0 + 2 * j + 1][d] << 16);
    ushort_t* dst = Vt + ((size_t)bh * 64 + d) * TSEQ + tt * 64 + t0;
    *(uint4*)dst       = make_uint4(wbuf[0], wbuf[1], wbuf[2], wbuf[3]);
    *(uint4*)(dst + 8) = make_uint4(wbuf[4], wbuf[5], wbuf[6], wbuf[7]);
}

// ---------------- LoRA rank-16 projection, 4-way K-split ----------------
__global__ void lora_t_part_kernel(const float* __restrict__ x,
                                   const float* __restrict__ la,
                                   float* __restrict__ tpart, int K) {
    __shared__ float Xs[16][64];
    const int tid = threadIdx.x;
    const int ty = tid >> 4, tx = tid & 15;
    const int row0 = blockIdx.x * 16;
    const int kbase = blockIdx.y * 256;
    float acc = 0.0f;
    for (int k0 = kbase; k0 < kbase + 256; k0 += 64) {
        int rr = tid >> 4, kk = (tid & 15) * 4;
        float4 v = *(const float4*)(x + (size_t)(row0 + rr) * K + k0 + kk);
        Xs[rr][kk] = v.x; Xs[rr][kk + 1] = v.y; Xs[rr][kk + 2] = v.z; Xs[rr][kk + 3] = v.w;
        __syncthreads();
        for (int k = 0; k < 64; ++k)
            acc += Xs[ty][k] * la[(size_t)(k0 + k) * RANK + tx];
        __syncthreads();
    }
    tpart[((size_t)blockIdx.y * M_TOTAL + row0 + ty) * RANK + tx] = acc;
}

__global__ void lora_t_part_bf16_kernel(const ushort_t* __restrict__ x,
                                        const float* __restrict__ la,
                                        float* __restrict__ tpart, int K) {
    __shared__ float Xs[16][64];
    const int tid = threadIdx.x;
    const int ty = tid >> 4, tx = tid & 15;
    const int row0 = blockIdx.x * 16;
    const int kbase = blockIdx.y * 256;
    float acc = 0.0f;
    for (int k0 = kbase; k0 < kbase + 256; k0 += 64) {
        int rr = tid >> 4, kk = (tid & 15) * 4;
        const ushort4 u = *(const ushort4*)(x + (size_t)(row0 + rr) * K + k0 + kk);
        Xs[rr][kk] = bfraw2f(u.x); Xs[rr][kk + 1] = bfraw2f(u.y);
        Xs[rr][kk + 2] = bfraw2f(u.z); Xs[rr][kk + 3] = bfraw2f(u.w);
        __syncthreads();
        for (int k = 0; k < 64; ++k)
            acc += Xs[ty][k] * la[(size_t)(k0 + k) * RANK + tx];
        __syncthreads();
    }
    tpart[((size_t)blockIdx.y * M_TOTAL + row0 + ty) * RANK + tx] = acc;
}

// ---------------- MFMA GEMM (128x128 tile, BK=64) ----------------
// out_mode 0: fp32 C.  out_mode 1: fused QKV epilogue -> bf16 Qb/Kb/Vb [bh][t][d]
// (Q scaled by 0.125, K/V fake-quantized).  SPLIT blocks with col0 >= split_col0
// use 3-MFMA hi/lo emulation; others plain bf16.
__device__ __forceinline__ int sw_off(int r, int c) {
    return ((r >> 1) << 7) + (((((r & 1) << 2) | c) ^ ((r >> 1) & 7)) << 4);
}

template <bool SPLIT>
__global__ __launch_bounds__(256)
void gemm_mfma_kernel(const __hip_bfloat16* __restrict__ Ah,
                      const __hip_bfloat16* __restrict__ Al,
                      const __hip_bfloat16* __restrict__ Bh,
                      const __hip_bfloat16* __restrict__ Bl,
                      const float* __restrict__ bias,
                      const float* __restrict__ tpart,
                      const float* __restrict__ lb,
                      float* __restrict__ Cf,
                      ushort_t* __restrict__ Qb,
                      ushort_t* __restrict__ Kb,
                      ushort_t* __restrict__ Vb,
                      const float* __restrict__ sp,
                      const float* __restrict__ zp,
                      int M, int N, int K, int split_col0, int out_mode) {
    constexpr int TILE32 = 128 * 32;            // elements per 128x32 sub-tile
    __shared__ __hip_bfloat16 As[(SPLIT ? 4 : 2) * TILE32];
    __shared__ __hip_bfloat16 Bs[(SPLIT ? 4 : 2) * TILE32];
    __shared__ float Ts[128 * 16];
    __shared__ float Ls[16 * 128];

    const int tid = threadIdx.x;
    const int lane = tid & 63, w = tid >> 6;
    const int row0 = blockIdx.y * 128, col0 = blockIdx.x * 128;
    const int wr = (w >> 1) * 64, wc = (w & 1) * 64;
    const bool do_split = SPLIT && (col0 >= split_col0);

    const int s_lc = (lane & 7) ^ ((lane >> 3) & 7);
    const int s_rb = 2 * (lane >> 3) + (s_lc >> 2);
    const int s_c8 = (s_lc & 3) * 8;

    float qsc = 0.f, qzp = 0.f;
    if (out_mode == 1) { qsc = sp[0]; qzp = zp[0]; }

    f32x4 acc[4][4];
    #pragma unroll
    for (int i = 0; i < 4; ++i)
        #pragma unroll
        for (int j = 0; j < 4; ++j)
            acc[i][j] = (f32x4){0.f, 0.f, 0.f, 0.f};

    const int arow = wr + (lane & 15);
    const int chunk = lane >> 4;

    for (int k0 = 0; k0 < K; k0 += 64) {
        // ---- stage both 32-wide sub-tiles ----
        #pragma unroll
        for (int qq = 0; qq < 4; ++qq) {
            const int q = 4 * w + qq;          // 0..15
            const int kk = q & 1, g = q >> 1;  // sub-tile, 16-row group
            const int r = 16 * g + s_rb;
            const int ksrc = k0 + kk * 32 + s_c8;
            const __hip_bfloat16* gA = Ah + (size_t)(row0 + r) * K + ksrc;
            __builtin_amdgcn_global_load_lds(
                (const __attribute__((address_space(1))) void*)gA,
                (__attribute__((address_space(3))) void*)(As + kk * TILE32 + g * 512), 16, 0, 0);
            const __hip_bfloat16* gB = Bh + (size_t)(col0 + r) * K + ksrc;
            __builtin_amdgcn_global_load_lds(
                (const __attribute__((address_space(1))) void*)gB,
                (__attribute__((address_space(3))) void*)(Bs + kk * TILE32 + g * 512), 16, 0, 0);
            if (do_split) {
                const __hip_bfloat16* gAl = Al + (size_t)(row0 + r) * K + ksrc;
                __builtin_amdgcn_global_load_lds(
                    (const __attribute__((address_space(1))) void*)gAl,
                    (__attribute__((address_space(3))) void*)(As + 2 * TILE32 + kk * TILE32 + g * 512), 16, 0, 0);
                const __hip_bfloat16* gBl = Bl + (size_t)(col0 + r) * K + ksrc;
                __builtin_amdgcn_global_load_lds(
                    (const __attribute__((address_space(1))) void*)gBl,
                    (__attribute__((address_space(3))) void*)(Bs + 2 * TILE32 + kk * TILE32 + g * 512), 16, 0, 0);
            }
        }
        __syncthreads();

        #pragma unroll
        for (int kk = 0; kk < 2; ++kk) {
            const char* ab = (const char*)As + kk * 8192;
            const char* bb = (const char*)Bs + kk * 8192;
            bf16x8 a_h[4], b_h[4], a_l[4], b_l[4];
            #pragma unroll
            for (int mi = 0; mi < 4; ++mi) {
                int off = sw_off(arow + mi * 16, chunk);
                a_h[mi] = *(const bf16x8*)(ab + off);
                if (do_split) a_l[mi] = *(const bf16x8*)(ab + 2 * TILE32 * 2 + off);
            }
            #pragma unroll
            for (int nj = 0; nj < 4; ++nj) {
                int off = sw_off(wc + nj * 16 + (lane & 15), chunk);
                b_h[nj] = *(const bf16x8*)(bb + off);
                if (do_split) b_l[nj] = *(const bf16x8*)(bb + 2 * TILE32 * 2 + off);
            }
            #pragma unroll
            for (int mi = 0; mi < 4; ++mi)
                #pragma unroll
                for (int nj = 0; nj < 4; ++nj) {
                    acc[mi][nj] = __builtin_amdgcn_mfma_f32_16x16x32_bf16(a_h[mi], b_h[nj], acc[mi][nj], 0, 0, 0);
                    if (do_split) {
                        acc[mi][nj] = __builtin_amdgcn_mfma_f32_16x16x32_bf16(a_h[mi], b_l[nj], acc[mi][nj], 0, 0, 0);
                        acc[mi][nj] = __builtin_amdgcn_mfma_f32_16x16x32_bf16(a_l[mi], b_h[nj], acc[mi][nj], 0, 0, 0);
                    }
                }
        }
        __syncthreads();
    }

    // ---- epilogue: bias + LORA_SCALE * ((sum of tparts) @ lb), then transform ----
    {
        int r = tid >> 1, j0 = (tid & 1) * 8;
        float4 t0 = {0, 0, 0, 0}, t1 = {0, 0, 0, 0};
        #pragma unroll
        for (int c = 0; c < 4; ++c) {
            const float* src = tpart + ((size_t)c * M_TOTAL + row0 + r) * RANK + j0;
            float4 s0 = *(const float4*)src;
            float4 s1 = *(const float4*)(src + 4);
            t0.x += s0.x; t0.y += s0.y; t0.z += s0.z; t0.w += s0.w;
            t1.x += s1.x; t1.y += s1.y; t1.z += s1.z; t1.w += s1.w;
        }
        *(float4*)(Ts + r * 16 + j0)     = t0;
        *(float4*)(Ts + r * 16 + j0 + 4) = t1;
        int rr = tid >> 4, c0 = (tid & 15) * 8;
        const float4* lsrc = (const float4*)(lb + (size_t)rr * N + col0 + c0);
        float4* ldst = (float4*)(Ls + rr * 128 + c0);
        ldst[0] = lsrc[0]; ldst[1] = lsrc[1];
    }
    __syncthreads();
    #pragma unroll
    for (int mi = 0; mi < 4; ++mi)
        #pragma unroll
        for (int nj = 0; nj < 4; ++nj) {
            const int coll = wc + nj * 16 + (lane & 15);
            const float bv = bias[col0 + coll];
            #pragma unroll
            for (int rg = 0; rg < 4; ++rg) {
                const int rowl = wr + mi * 16 + (lane >> 4) * 4 + rg;
                float lsum = 0.f;
                #pragma unroll
                for (int rr = 0; rr < 16; ++rr)
                    lsum += Ts[rowl * 16 + rr] * Ls[rr * 128 + coll];
                const float val = acc[mi][nj][rg] + bv + LORA_SCALE * lsum;
                if (out_mode == 0) {
                    Cf[(size_t)(row0 + rowl) * N + col0 + coll] = val;
                } else {
                    const int R = row0 + rowl;
                    const int b = R >> 11, t = R & 2047;
                    const int CN = col0 + coll;
                    const int sec = CN >> 10, head = (CN >> 6) & 15, d = CN & 63;
                    const size_t off = (((size_t)(b * 16 + head)) * TSEQ + t) * 64 + d;
                    if (sec == 0)      Qb[off] = bf16bits(val * 0.125f);
                    else if (sec == 1) Kb[off] = bf16bits(fake_quant(val, qsc, qzp));
                    else               Vb[off] = bf16bits(fake_quant(val, qsc, qzp));
                }
            }
        }
}

// ---------------- MFMA flash attention ----------------
__global__ __launch_bounds__(256)
void mfma_attn_kernel(const ushort_t* __restrict__ Qb,   // [bh][T][64] (x0.125)
                      const ushort_t* __restrict__ Kq,   // [bh][T][64]
                      const ushort_t* __restrict__ Vtq,  // [bh][64][T]
                      ushort_t* __restrict__ outb) {     // [B][T][1024] bf16
    const int bx = blockIdx.x;
    const int bh = bx & 31;
    const int qt = 31 - (bx >> 5);                 // heavy q-tiles dispatch first
    const int b = bh >> 4, h = bh & 15;
    const int tid = threadIdx.x;
    const int lane = tid & 63, w = tid >> 6;
    const int m16 = lane & 15, qc = lane >> 4;
    const int m7 = m16 & 7;

    __shared__ ushort_t Qs[4096];
    __shared__ ushort_t Ks[4096];
    __shared__ ushort_t Vs[4096];
    __shared__ ushort_t Ps[4096];

    const int s_g = (lane & 7) ^ ((lane >> 3) & 7);
    const int s_r = lane >> 3;

    const ushort_t* Qg = Qb + (size_t)bh * TSEQ * 64;
    const ushort_t* Kg = Kq + (size_t)bh * TSEQ * 64;
    const ushort_t* Vg = Vtq + (size_t)bh * 64 * TSEQ;

    // ---- stage Q once (bf16, pre-scaled) ----
    #pragma unroll
    for (int pp = 0; pp < 2; ++pp) {
        const int p = 2 * w + pp;
        const ushort_t* gq = Qg + ((size_t)(qt * 64 + 8 * p + s_r)) * 64 + s_g * 8;
        __builtin_amdgcn_global_load_lds(
            (const __attribute__((address_space(1))) void*)gq,
            (__attribute__((address_space(3))) void*)(Qs + p * 512), 16, 0, 0);
    }
    __syncthreads();

    bf16x8 a_q[2];
    {
        const int row = 16 * w + m16;
        #pragma unroll
        for (int c = 0; c < 2; ++c) {
            const int g = qc + 4 * c;
            a_q[c] = *(const bf16x8*)((const char*)Qs + row * 128 + ((g ^ m7) << 4));
        }
    }

    float m_st[4], l_st[4];
    f32x4 o_acc[4];
    #pragma unroll
    for (int r = 0; r < 4; ++r) { m_st[r] = -INFINITY; l_st[r] = 0.0f; }
    #pragma unroll
    for (int dj = 0; dj < 4; ++dj) o_acc[dj] = (f32x4){0.f, 0.f, 0.f, 0.f};

    for (int kt = 0; kt <= qt; ++kt) {
        __syncthreads();
        #pragma unroll
        for (int pp = 0; pp < 2; ++pp) {
            const int p = 2 * w + pp;
            const ushort_t* gk = Kg + ((size_t)(kt * 64 + 8 * p + s_r)) * 64 + s_g * 8;
            __builtin_amdgcn_global_load_lds(
                (const __attribute__((address_space(1))) void*)gk,
                (__attribute__((address_space(3))) void*)(Ks + p * 512), 16, 0, 0);
            const ushort_t* gv = Vg + ((size_t)(8 * p + s_r)) * TSEQ + kt * 64 + s_g * 8;
            __builtin_amdgcn_global_load_lds(
                (const __attribute__((address_space(1))) void*)gv,
                (__attribute__((address_space(3))) void*)(Vs + p * 512), 16, 0, 0);
        }
        __syncthreads();

        const bool diag = (kt == qt);
        const int nj_hi = diag ? (w + 1) : 4;

        f32x4 s[4];
        #pragma unroll
        for (int nj = 0; nj < 4; ++nj) s[nj] = (f32x4){0.f, 0.f, 0.f, 0.f};
        #pragma unroll
        for (int c = 0; c < 2; ++c) {
            #pragma unroll
            for (int nj = 0; nj < 4; ++nj) {
                if (nj < nj_hi) {
                    const int row = 16 * nj + m16;
                    const int g = qc + 4 * c;
                    bf16x8 bk = *(const bf16x8*)((const char*)Ks + row * 128 + ((g ^ m7) << 4));
                    s[nj] = __builtin_amdgcn_mfma_f32_16x16x32_bf16(a_q[c], bk, s[nj], 0, 0, 0);
                }
            }
        }

        float alpha[4], p_[4][4];
        #pragma unroll
        for (int reg = 0; reg < 4; ++reg) {
            const int qrow = 16 * w + 4 * qc + reg;
            float sv[4];
            float rm = -INFINITY;
            #pragma unroll
            for (int nj = 0; nj < 4; ++nj) {
                float v = s[nj][reg];
                if (diag && (m16 + 16 * nj > qrow)) v = -INFINITY;
                sv[nj] = v;
                rm = fmaxf(rm, v);
            }
            #pragma unroll
            for (int off = 1; off < 16; off <<= 1)
                rm = fmaxf(rm, __shfl_xor(rm, off, 16));
            const float mo = m_st[reg];
            const float mn = fmaxf(mo, rm);
            const float al = __expf(mo - mn);
            float rs = 0.f;
            #pragma unroll
            for (int nj = 0; nj < 4; ++nj) {
                float pv = __expf(sv[nj] - mn);
                p_[reg][nj] = pv;
                rs += pv;
            }
            #pragma unroll
            for (int off = 1; off < 16; off <<= 1)
                rs += __shfl_xor(rs, off, 16);
            l_st[reg] = al * l_st[reg] + rs;
            m_st[reg] = mn;
            alpha[reg] = al;
        }

        #pragma unroll
        for (int reg = 0; reg < 4; ++reg) {
            const int row = 16 * w + 4 * qc + reg;
            const int r7 = row & 7;
            #pragma unroll
            for (int nj = 0; nj < 4; ++nj) {
                const int k = m16 + 16 * nj;
                Ps[row * 64 + (((k >> 3) ^ r7) << 3) + (k & 7)] = bf16bits(p_[reg][nj]);
            }
        }

        #pragma unroll
        for (int dj = 0; dj < 4; ++dj)
            #pragma unroll
            for (int reg = 0; reg < 4; ++reg)
                o_acc[dj][reg] *= alpha[reg];

        const int c_hi = diag ? (w >= 2 ? 2 : 1) : 2;
        #pragma unroll
        for (int c = 0; c < 2; ++c) {
            if (c < c_hi) {
                const int rowp = 16 * w + m16;
                const int g = qc + 4 * c;
                bf16x8 ap = *(const bf16x8*)((const char*)Ps + rowp * 128 + ((g ^ m7) << 4));
                #pragma unroll
                for (int dj = 0; dj < 4; ++dj) {
                    const int rowv = 16 * dj + m16;
                    bf16x8 bv = *(const bf16x8*)((const char*)Vs + rowv * 128 + ((g ^ m7) << 4));
                    o_acc[dj] = __builtin_amdgcn_mfma_f32_16x16x32_bf16(ap, bv, o_acc[dj], 0, 0, 0);
                }
            }
        }
    }

    #pragma unroll
    for (int reg = 0; reg < 4; ++reg) {
        const float inv = 1.0f / l_st[reg];
        const int q = qt * 64 + 16 * w + 4 * qc + reg;
        #pragma unroll
        for (int dj = 0; dj < 4; ++dj) {
            const int d = m16 + 16 * dj;
            outb[((size_t)b * TSEQ + q) * N_EMBD + h * 64 + d] = bf16bits(o_acc[dj][reg] * inv);
        }
    }
}

extern "C" void kernel_launch(void* const* d_in, const int* in_sizes, int n_in,
                              void* d_out, int out_size, void* d_ws, size_t ws_size,
                              hipStream_t stream) {
    const float* x        = (const float*)d_in[0];
    const float* w_attn   = (const float*)d_in[1];
    const float* b_attn   = (const float*)d_in[2];
    const float* la_attn  = (const float*)d_in[3];
    const float* lb_attn  = (const float*)d_in[4];
    const float* w_proj   = (const float*)d_in[5];
    const float* b_proj   = (const float*)d_in[6];
    const float* la_proj  = (const float*)d_in[7];
    const float* lb_proj  = (const float*)d_in[8];
    const float* kv_scale = (const float*)d_in[9];
    const float* kv_zp    = (const float*)d_in[10];
    float* out = (float*)d_out;

    char* ws = (char*)d_ws;
    float* t_attn_p       = (float*)ws;          ws += (size_t)4 * M_TOTAL * RANK * 4;
    float* t_proj_p       = (float*)ws;          ws += (size_t)4 * M_TOTAL * RANK * 4;
    ushort_t* aob         = (ushort_t*)ws;       ws += (size_t)M_TOTAL * N_EMBD * 2;
    __hip_bfloat16* x_hi  = (__hip_bfloat16*)ws; ws += (size_t)M_TOTAL * N_EMBD * 2;
    __hip_bfloat16* x_lo  = (__hip_bfloat16*)ws; ws += (size_t)M_TOTAL * N_EMBD * 2;
    __hip_bfloat16* wqT_h = (__hip_bfloat16*)ws; ws += (size_t)C3 * N_EMBD * 2;
    __hip_bfloat16* wqT_l = (__hip_bfloat16*)ws; ws += (size_t)C3 * N_EMBD * 2;
    __hip_bfloat16* wpT   = (__hip_bfloat16*)ws; ws += (size_t)N_EMBD * N_EMBD * 2;
    ushort_t* Qb          = (ushort_t*)ws;       ws += (size_t)32 * TSEQ * 64 * 2;
    ushort_t* Kb          = (ushort_t*)ws;       ws += (size_t)32 * TSEQ * 64 * 2;
    ushort_t* Vb          = (ushort_t*)ws;       ws += (size_t)32 * TSEQ * 64 * 2;
    ushort_t* Vtq         = (ushort_t*)ws;       ws += (size_t)32 * 64 * TSEQ * 2;

    cvt_split_kernel<<<dim3(M_TOTAL * N_EMBD / 4 / 256), 256, 0, stream>>>(
        x, x_hi, x_lo, M_TOTAL * N_EMBD / 4);
    transpose_split_kernel<<<dim3(C3 / 32, N_EMBD / 32), 256, 0, stream>>>(
        w_attn, wqT_h, wqT_l, N_EMBD, C3);
    transpose_split_kernel<<<dim3(N_EMBD / 32, N_EMBD / 32), 256, 0, stream>>>(
        w_proj, wpT, nullptr, N_EMBD, N_EMBD);
    lora_t_part_kernel<<<dim3(M_TOTAL / 16, 4), 256, 0, stream>>>(x, la_attn, t_attn_p, N_EMBD);

    gemm_mfma_kernel<true><<<dim3(C3 / 128, M_TOTAL / 128), 256, 0, stream>>>(
        x_hi, x_lo, wqT_h, wqT_l, b_attn, t_attn_p, lb_attn,
        nullptr, Qb, Kb, Vb, kv_scale, kv_zp,
        M_TOTAL, C3, N_EMBD, N_EMBD, 1);

    vtrans_kernel<<<dim3(32 * (TSEQ / 64)), 256, 0, stream>>>(Vb, Vtq);

    mfma_attn_kernel<<<dim3(32 * 32), 256, 0, stream>>>(Qb, Kb, Vtq, aob);

    lora_t_part_bf16_kernel<<<dim3(M_TOTAL / 16, 4), 256, 0, stream>>>(aob, la_proj, t_proj_p, N_EMBD);

    gemm_mfma_kernel<false><<<dim3(N_EMBD / 128, M_TOTAL / 128), 256, 0, stream>>>(
        (const __hip_bfloat16*)aob, nullptr, wpT, nullptr, b_proj, t_proj_p, lb_proj,
        out, nullptr, nullptr, nullptr, nullptr, nullptr,
        M_TOTAL, N_EMBD, N_EMBD, 1 << 30, 0);
}

// Round 7
// 351.971 us; speedup vs baseline: 14.1984x; 1.0863x over previous
//
#include <hip/hip_runtime.h>
#include <hip/hip_bf16.h>
#include <math.h>

#define N_EMBD   1024
#define N_HEAD   16
#define HEAD_DIM 64
#define BATCH    2
#define TSEQ     2048
#define RANK     16
#define LORA_SCALE 2.0f
#define M_TOTAL  (BATCH * TSEQ)   // 4096
#define C3       (3 * N_EMBD)     // 3072

typedef unsigned short ushort_t;
typedef __attribute__((ext_vector_type(8))) short bf16x8;
typedef __attribute__((ext_vector_type(4))) float f32x4;

__device__ __forceinline__ float fake_quant(float x, float scale, float zp) {
    float q = rintf(x / scale + zp);
    q = fminf(fmaxf(q, 0.0f), 255.0f);
    return (q - zp) * scale;
}

__device__ __forceinline__ ushort_t bf16bits(float f) {
    union { __hip_bfloat16 h; ushort_t u; } c;
    c.h = __float2bfloat16(f);
    return c.u;
}

__device__ __forceinline__ float bfraw2f(ushort_t u) {
    union { unsigned int i; float f; } c; c.i = ((unsigned int)u) << 16; return c.f;
}

// ---------------- conversion kernels ----------------
__global__ void cvt_split_kernel(const float* __restrict__ in,
                                 __hip_bfloat16* __restrict__ hi,
                                 __hip_bfloat16* __restrict__ lo, int n4) {
    int i = blockIdx.x * 256 + threadIdx.x;
    if (i >= n4) return;
    float4 v = ((const float4*)in)[i];
    float vs[4] = {v.x, v.y, v.z, v.w};
    #pragma unroll
    for (int k = 0; k < 4; ++k) {
        __hip_bfloat16 h = __float2bfloat16(vs[k]);
        hi[i * 4 + k] = h;
        lo[i * 4 + k] = __float2bfloat16(vs[k] - __bfloat162float(h));
    }
}

__global__ void transpose_split_kernel(const float* __restrict__ in,
                                       __hip_bfloat16* __restrict__ hiT,
                                       __hip_bfloat16* __restrict__ loT,
                                       int R, int C) {
    __shared__ float tl[32][33];
    const int c0 = blockIdx.x * 32, r0 = blockIdx.y * 32;
    const int tx = threadIdx.x & 31, ty = threadIdx.x >> 5;
    for (int i = ty; i < 32; i += 8)
        tl[i][tx] = in[(size_t)(r0 + i) * C + c0 + tx];
    __syncthreads();
    for (int i = ty; i < 32; i += 8) {
        float v = tl[tx][i];
        __hip_bfloat16 h = __float2bfloat16(v);
        size_t o = (size_t)(c0 + i) * R + r0 + tx;
        hiT[o] = h;
        if (loT) loT[o] = __float2bfloat16(v - __bfloat162float(h));
    }
}

// Vb[bh][t][d] -> Vt[bh][d][t]  (bf16 transpose, 64x64 tiles)
__global__ void vtrans_kernel(const ushort_t* __restrict__ Vb,
                              ushort_t* __restrict__ Vt) {
    __shared__ ushort_t tl[64][68];
    const int bh = blockIdx.x & 31, tt = blockIdx.x >> 5;
    const int tid = threadIdx.x;
    {
        const int t = tid >> 2, d0 = (tid & 3) * 16;
        const uint4 u = *(const uint4*)(Vb + ((size_t)bh * TSEQ + tt * 64 + t) * 64 + d0);
        *(uint4*)&tl[t][d0] = u;
        *(uint4*)&tl[t][d0 + 8] = *(const uint4*)(Vb + ((size_t)bh * TSEQ + tt * 64 + t) * 64 + d0 + 8);
    }
    __syncthreads();
    const int d = tid >> 2, t0 = (tid & 3) * 16;
    unsigned int wbuf[8];
    #pragma unroll
    for (int j = 0; j < 8; ++j)
        wbuf[j] = (unsigned int)tl[t0 + 2 * j][d] | ((unsigned int)tl[t0 + 2 * j + 1][d] << 16);
    ushort_t* dst = Vt + ((size_t)bh * 64 + d) * TSEQ + tt * 64 + t0;
    *(uint4*)dst       = make_uint4(wbuf[0], wbuf[1], wbuf[2], wbuf[3]);
    *(uint4*)(dst + 8) = make_uint4(wbuf[4], wbuf[5], wbuf[6], wbuf[7]);
}

// ---------------- LoRA rank-16 projection, 4-way K-split ----------------
__global__ void lora_t_part_kernel(const float* __restrict__ x,
                                   const float* __restrict__ la,
                                   float* __restrict__ tpart, int K) {
    __shared__ float Xs[16][64];
    const int tid = threadIdx.x;
    const int ty = tid >> 4, tx = tid & 15;
    const int row0 = blockIdx.x * 16;
    const int kbase = blockIdx.y * 256;
    float acc = 0.0f;
    for (int k0 = kbase; k0 < kbase + 256; k0 += 64) {
        int rr = tid >> 4, kk = (tid & 15) * 4;
        float4 v = *(const float4*)(x + (size_t)(row0 + rr) * K + k0 + kk);
        Xs[rr][kk] = v.x; Xs[rr][kk + 1] = v.y; Xs[rr][kk + 2] = v.z; Xs[rr][kk + 3] = v.w;
        __syncthreads();
        for (int k = 0; k < 64; ++k)
            acc += Xs[ty][k] * la[(size_t)(k0 + k) * RANK + tx];
        __syncthreads();
    }
    tpart[((size_t)blockIdx.y * M_TOTAL + row0 + ty) * RANK + tx] = acc;
}

__global__ void lora_t_part_bf16_kernel(const ushort_t* __restrict__ x,
                                        const float* __restrict__ la,
                                        float* __restrict__ tpart, int K) {
    __shared__ float Xs[16][64];
    const int tid = threadIdx.x;
    const int ty = tid >> 4, tx = tid & 15;
    const int row0 = blockIdx.x * 16;
    const int kbase = blockIdx.y * 256;
    float acc = 0.0f;
    for (int k0 = kbase; k0 < kbase + 256; k0 += 64) {
        int rr = tid >> 4, kk = (tid & 15) * 4;
        const ushort4 u = *(const ushort4*)(x + (size_t)(row0 + rr) * K + k0 + kk);
        Xs[rr][kk] = bfraw2f(u.x); Xs[rr][kk + 1] = bfraw2f(u.y);
        Xs[rr][kk + 2] = bfraw2f(u.z); Xs[rr][kk + 3] = bfraw2f(u.w);
        __syncthreads();
        for (int k = 0; k < 64; ++k)
            acc += Xs[ty][k] * la[(size_t)(k0 + k) * RANK + tx];
        __syncthreads();
    }
    tpart[((size_t)blockIdx.y * M_TOTAL + row0 + ty) * RANK + tx] = acc;
}

// ---------------- MFMA GEMM (128x128 tile, BK=32, 3 blocks/CU) ----------------
// out_mode 0: fp32 C.  out_mode 1: fused QKV epilogue -> bf16 Qb/Kb/Vb [bh][t][d]
// (Q x0.125, K/V fake-quantized). Blocks with col0 >= split_col0 use 3-MFMA
// hi/lo split.  NOTE: no LDS union (round-6 union raced warm-vs-cold).
__device__ __forceinline__ int sw_off(int r, int c) {
    return ((r >> 1) << 7) + (((((r & 1) << 2) | c) ^ ((r >> 1) & 7)) << 4);
}

template <bool SPLIT>
__global__ __launch_bounds__(256, 3)
void gemm_mfma_kernel(const __hip_bfloat16* __restrict__ Ah,
                      const __hip_bfloat16* __restrict__ Al,
                      const __hip_bfloat16* __restrict__ Bh,
                      const __hip_bfloat16* __restrict__ Bl,
                      const float* __restrict__ bias,
                      const float* __restrict__ tpart,
                      const float* __restrict__ lb,
                      float* __restrict__ Cf,
                      ushort_t* __restrict__ Qb,
                      ushort_t* __restrict__ Kb,
                      ushort_t* __restrict__ Vb,
                      const float* __restrict__ sp,
                      const float* __restrict__ zp,
                      int M, int N, int K, int split_col0, int out_mode) {
    constexpr int TILE = 128 * 32;              // bf16 elements per 128x32 tile
    __shared__ __hip_bfloat16 As[(SPLIT ? 2 : 1) * TILE];
    __shared__ __hip_bfloat16 Bs[(SPLIT ? 2 : 1) * TILE];
    __shared__ float Ts[128 * 16];
    __shared__ float Ls[16 * 128];

    const int tid = threadIdx.x;
    const int lane = tid & 63, w = tid >> 6;
    const int row0 = blockIdx.y * 128, col0 = blockIdx.x * 128;
    const int wr = (w >> 1) * 64, wc = (w & 1) * 64;
    const bool do_split = SPLIT && (col0 >= split_col0);

    const int s_lc = (lane & 7) ^ ((lane >> 3) & 7);
    const int s_rb = 2 * (lane >> 3) + (s_lc >> 2);
    const int s_c8 = (s_lc & 3) * 8;

    float qsc = 0.f, qzp = 0.f;
    if (out_mode == 1) { qsc = sp[0]; qzp = zp[0]; }

    f32x4 acc[4][4];
    #pragma unroll
    for (int i = 0; i < 4; ++i)
        #pragma unroll
        for (int j = 0; j < 4; ++j)
            acc[i][j] = (f32x4){0.f, 0.f, 0.f, 0.f};

    const int arow = wr + (lane & 15);
    const int chunk = lane >> 4;

    for (int k0 = 0; k0 < K; k0 += 32) {
        #pragma unroll
        for (int qq = 0; qq < 2; ++qq) {
            const int q = 2 * w + qq;          // 16-row group 0..7
            const int r = 16 * q + s_rb;
            const __hip_bfloat16* gA = Ah + (size_t)(row0 + r) * K + k0 + s_c8;
            __builtin_amdgcn_global_load_lds(
                (const __attribute__((address_space(1))) void*)gA,
                (__attribute__((address_space(3))) void*)(As + q * 512), 16, 0, 0);
            const __hip_bfloat16* gB = Bh + (size_t)(col0 + r) * K + k0 + s_c8;
            __builtin_amdgcn_global_load_lds(
                (const __attribute__((address_space(1))) void*)gB,
                (__attribute__((address_space(3))) void*)(Bs + q * 512), 16, 0, 0);
            if (do_split) {
                const __hip_bfloat16* gAl = Al + (size_t)(row0 + r) * K + k0 + s_c8;
                __builtin_amdgcn_global_load_lds(
                    (const __attribute__((address_space(1))) void*)gAl,
                    (__attribute__((address_space(3))) void*)(As + TILE + q * 512), 16, 0, 0);
                const __hip_bfloat16* gBl = Bl + (size_t)(col0 + r) * K + k0 + s_c8;
                __builtin_amdgcn_global_load_lds(
                    (const __attribute__((address_space(1))) void*)gBl,
                    (__attribute__((address_space(3))) void*)(Bs + TILE + q * 512), 16, 0, 0);
            }
        }
        __syncthreads();

        const char* ab = (const char*)As;
        const char* bb = (const char*)Bs;
        bf16x8 a_h[4], b_h[4], a_l[4], b_l[4];
        #pragma unroll
        for (int mi = 0; mi < 4; ++mi) {
            int off = sw_off(arow + mi * 16, chunk);
            a_h[mi] = *(const bf16x8*)(ab + off);
            if (do_split) a_l[mi] = *(const bf16x8*)(ab + 2 * TILE + off);
        }
        #pragma unroll
        for (int nj = 0; nj < 4; ++nj) {
            int off = sw_off(wc + nj * 16 + (lane & 15), chunk);
            b_h[nj] = *(const bf16x8*)(bb + off);
            if (do_split) b_l[nj] = *(const bf16x8*)(bb + 2 * TILE + off);
        }
        #pragma unroll
        for (int mi = 0; mi < 4; ++mi)
            #pragma unroll
            for (int nj = 0; nj < 4; ++nj) {
                acc[mi][nj] = __builtin_amdgcn_mfma_f32_16x16x32_bf16(a_h[mi], b_h[nj], acc[mi][nj], 0, 0, 0);
                if (do_split) {
                    acc[mi][nj] = __builtin_amdgcn_mfma_f32_16x16x32_bf16(a_h[mi], b_l[nj], acc[mi][nj], 0, 0, 0);
                    acc[mi][nj] = __builtin_amdgcn_mfma_f32_16x16x32_bf16(a_l[mi], b_h[nj], acc[mi][nj], 0, 0, 0);
                }
            }
        __syncthreads();
    }

    // ---- epilogue: bias + LORA_SCALE * ((sum of tparts) @ lb) ----
    {
        int r = tid >> 1, j0 = (tid & 1) * 8;
        float4 t0 = {0, 0, 0, 0}, t1 = {0, 0, 0, 0};
        #pragma unroll
        for (int c = 0; c < 4; ++c) {
            const float* src = tpart + ((size_t)c * M_TOTAL + row0 + r) * RANK + j0;
            float4 s0 = *(const float4*)src;
            float4 s1 = *(const float4*)(src + 4);
            t0.x += s0.x; t0.y += s0.y; t0.z += s0.z; t0.w += s0.w;
            t1.x += s1.x; t1.y += s1.y; t1.z += s1.z; t1.w += s1.w;
        }
        *(float4*)(Ts + r * 16 + j0)     = t0;
        *(float4*)(Ts + r * 16 + j0 + 4) = t1;
        int rr = tid >> 4, c0 = (tid & 15) * 8;
        const float4* lsrc = (const float4*)(lb + (size_t)rr * N + col0 + c0);
        float4* ldst = (float4*)(Ls + rr * 128 + c0);
        ldst[0] = lsrc[0]; ldst[1] = lsrc[1];
    }
    __syncthreads();
    #pragma unroll
    for (int mi = 0; mi < 4; ++mi)
        #pragma unroll
        for (int nj = 0; nj < 4; ++nj) {
            const int coll = wc + nj * 16 + (lane & 15);
            const float bv = bias[col0 + coll];
            #pragma unroll
            for (int rg = 0; rg < 4; ++rg) {
                const int rowl = wr + mi * 16 + (lane >> 4) * 4 + rg;
                float lsum = 0.f;
                #pragma unroll
                for (int rr = 0; rr < 16; ++rr)
                    lsum += Ts[rowl * 16 + rr] * Ls[rr * 128 + coll];
                const float val = acc[mi][nj][rg] + bv + LORA_SCALE * lsum;
                if (out_mode == 0) {
                    Cf[(size_t)(row0 + rowl) * N + col0 + coll] = val;
                } else {
                    const int R = row0 + rowl;
                    const int b = R >> 11, t = R & 2047;
                    const int CN = col0 + coll;
                    const int sec = CN >> 10, head = (CN >> 6) & 15, d = CN & 63;
                    const size_t off = (((size_t)(b * 16 + head)) * TSEQ + t) * 64 + d;
                    if (sec == 0)      Qb[off] = bf16bits(val * 0.125f);
                    else if (sec == 1) Kb[off] = bf16bits(fake_quant(val, qsc, qzp));
                    else               Vb[off] = bf16bits(fake_quant(val, qsc, qzp));
                }
            }
        }
}

// ---------------- MFMA flash attention ----------------
__global__ __launch_bounds__(256)
void mfma_attn_kernel(const ushort_t* __restrict__ Qb,   // [bh][T][64] (x0.125)
                      const ushort_t* __restrict__ Kq,   // [bh][T][64]
                      const ushort_t* __restrict__ Vtq,  // [bh][64][T]
                      ushort_t* __restrict__ outb) {     // [B][T][1024] bf16
    const int bx = blockIdx.x;
    const int bh = bx & 31;
    const int qt = 31 - (bx >> 5);                 // heavy q-tiles dispatch first
    const int b = bh >> 4, h = bh & 15;
    const int tid = threadIdx.x;
    const int lane = tid & 63, w = tid >> 6;
    const int m16 = lane & 15, qc = lane >> 4;
    const int m7 = m16 & 7;

    __shared__ ushort_t Qs[4096];
    __shared__ ushort_t Ks[4096];
    __shared__ ushort_t Vs[4096];
    __shared__ ushort_t Ps[4096];

    const int s_g = (lane & 7) ^ ((lane >> 3) & 7);
    const int s_r = lane >> 3;

    const ushort_t* Qg = Qb + (size_t)bh * TSEQ * 64;
    const ushort_t* Kg = Kq + (size_t)bh * TSEQ * 64;
    const ushort_t* Vg = Vtq + (size_t)bh * 64 * TSEQ;

    #pragma unroll
    for (int pp = 0; pp < 2; ++pp) {
        const int p = 2 * w + pp;
        const ushort_t* gq = Qg + ((size_t)(qt * 64 + 8 * p + s_r)) * 64 + s_g * 8;
        __builtin_amdgcn_global_load_lds(
            (const __attribute__((address_space(1))) void*)gq,
            (__attribute__((address_space(3))) void*)(Qs + p * 512), 16, 0, 0);
    }
    __syncthreads();

    bf16x8 a_q[2];
    {
        const int row = 16 * w + m16;
        #pragma unroll
        for (int c = 0; c < 2; ++c) {
            const int g = qc + 4 * c;
            a_q[c] = *(const bf16x8*)((const char*)Qs + row * 128 + ((g ^ m7) << 4));
        }
    }

    float m_st[4], l_st[4];
    f32x4 o_acc[4];
    #pragma unroll
    for (int r = 0; r < 4; ++r) { m_st[r] = -INFINITY; l_st[r] = 0.0f; }
    #pragma unroll
    for (int dj = 0; dj < 4; ++dj) o_acc[dj] = (f32x4){0.f, 0.f, 0.f, 0.f};

    for (int kt = 0; kt <= qt; ++kt) {
        __syncthreads();
        #pragma unroll
        for (int pp = 0; pp < 2; ++pp) {
            const int p = 2 * w + pp;
            const ushort_t* gk = Kg + ((size_t)(kt * 64 + 8 * p + s_r)) * 64 + s_g * 8;
            __builtin_amdgcn_global_load_lds(
                (const __attribute__((address_space(1))) void*)gk,
                (__attribute__((address_space(3))) void*)(Ks + p * 512), 16, 0, 0);
            const ushort_t* gv = Vg + ((size_t)(8 * p + s_r)) * TSEQ + kt * 64 + s_g * 8;
            __builtin_amdgcn_global_load_lds(
                (const __attribute__((address_space(1))) void*)gv,
                (__attribute__((address_space(3))) void*)(Vs + p * 512), 16, 0, 0);
        }
        __syncthreads();

        const bool diag = (kt == qt);
        const int nj_hi = diag ? (w + 1) : 4;

        f32x4 s[4];
        #pragma unroll
        for (int nj = 0; nj < 4; ++nj) s[nj] = (f32x4){0.f, 0.f, 0.f, 0.f};
        #pragma unroll
        for (int c = 0; c < 2; ++c) {
            #pragma unroll
            for (int nj = 0; nj < 4; ++nj) {
                if (nj < nj_hi) {
                    const int row = 16 * nj + m16;
                    const int g = qc + 4 * c;
                    bf16x8 bk = *(const bf16x8*)((const char*)Ks + row * 128 + ((g ^ m7) << 4));
                    s[nj] = __builtin_amdgcn_mfma_f32_16x16x32_bf16(a_q[c], bk, s[nj], 0, 0, 0);
                }
            }
        }

        float alpha[4], p_[4][4];
        #pragma unroll
        for (int reg = 0; reg < 4; ++reg) {
            const int qrow = 16 * w + 4 * qc + reg;
            float sv[4];
            float rm = -INFINITY;
            #pragma unroll
            for (int nj = 0; nj < 4; ++nj) {
                float v = s[nj][reg];
                if (diag && (m16 + 16 * nj > qrow)) v = -INFINITY;
                sv[nj] = v;
                rm = fmaxf(rm, v);
            }
            #pragma unroll
            for (int off = 1; off < 16; off <<= 1)
                rm = fmaxf(rm, __shfl_xor(rm, off, 16));
            const float mo = m_st[reg];
            const float mn = fmaxf(mo, rm);
            const float al = __expf(mo - mn);
            float rs = 0.f;
            #pragma unroll
            for (int nj = 0; nj < 4; ++nj) {
                float pv = __expf(sv[nj] - mn);
                p_[reg][nj] = pv;
                rs += pv;
            }
            #pragma unroll
            for (int off = 1; off < 16; off <<= 1)
                rs += __shfl_xor(rs, off, 16);
            l_st[reg] = al * l_st[reg] + rs;
            m_st[reg] = mn;
            alpha[reg] = al;
        }

        #pragma unroll
        for (int reg = 0; reg < 4; ++reg) {
            const int row = 16 * w + 4 * qc + reg;
            const int r7 = row & 7;
            #pragma unroll
            for (int nj = 0; nj < 4; ++nj) {
                const int k = m16 + 16 * nj;
                Ps[row * 64 + (((k >> 3) ^ r7) << 3) + (k & 7)] = bf16bits(p_[reg][nj]);
            }
        }

        #pragma unroll
        for (int dj = 0; dj < 4; ++dj)
            #pragma unroll
            for (int reg = 0; reg < 4; ++reg)
                o_acc[dj][reg] *= alpha[reg];

        const int c_hi = diag ? (w >= 2 ? 2 : 1) : 2;
        #pragma unroll
        for (int c = 0; c < 2; ++c) {
            if (c < c_hi) {
                const int rowp = 16 * w + m16;
                const int g = qc + 4 * c;
                bf16x8 ap = *(const bf16x8*)((const char*)Ps + rowp * 128 + ((g ^ m7) << 4));
                #pragma unroll
                for (int dj = 0; dj < 4; ++dj) {
                    const int rowv = 16 * dj + m16;
                    bf16x8 bv = *(const bf16x8*)((const char*)Vs + rowv * 128 + ((g ^ m7) << 4));
                    o_acc[dj] = __builtin_amdgcn_mfma_f32_16x16x32_bf16(ap, bv, o_acc[dj], 0, 0, 0);
                }
            }
        }
    }

    #pragma unroll
    for (int reg = 0; reg < 4; ++reg) {
        const float inv = 1.0f / l_st[reg];
        const int q = qt * 64 + 16 * w + 4 * qc + reg;
        #pragma unroll
        for (int dj = 0; dj < 4; ++dj) {
            const int d = m16 + 16 * dj;
            outb[((size_t)b * TSEQ + q) * N_EMBD + h * 64 + d] = bf16bits(o_acc[dj][reg] * inv);
        }
    }
}

extern "C" void kernel_launch(void* const* d_in, const int* in_sizes, int n_in,
                              void* d_out, int out_size, void* d_ws, size_t ws_size,
                              hipStream_t stream) {
    const float* x        = (const float*)d_in[0];
    const float* w_attn   = (const float*)d_in[1];
    const float* b_attn   = (const float*)d_in[2];
    const float* la_attn  = (const float*)d_in[3];
    const float* lb_attn  = (const float*)d_in[4];
    const float* w_proj   = (const float*)d_in[5];
    const float* b_proj   = (const float*)d_in[6];
    const float* la_proj  = (const float*)d_in[7];
    const float* lb_proj  = (const float*)d_in[8];
    const float* kv_scale = (const float*)d_in[9];
    const float* kv_zp    = (const float*)d_in[10];
    float* out = (float*)d_out;

    char* ws = (char*)d_ws;
    float* t_attn_p       = (float*)ws;          ws += (size_t)4 * M_TOTAL * RANK * 4;
    float* t_proj_p       = (float*)ws;          ws += (size_t)4 * M_TOTAL * RANK * 4;
    ushort_t* aob         = (ushort_t*)ws;       ws += (size_t)M_TOTAL * N_EMBD * 2;
    __hip_bfloat16* x_hi  = (__hip_bfloat16*)ws; ws += (size_t)M_TOTAL * N_EMBD * 2;
    __hip_bfloat16* x_lo  = (__hip_bfloat16*)ws; ws += (size_t)M_TOTAL * N_EMBD * 2;
    __hip_bfloat16* wqT_h = (__hip_bfloat16*)ws; ws += (size_t)C3 * N_EMBD * 2;
    __hip_bfloat16* wqT_l = (__hip_bfloat16*)ws; ws += (size_t)C3 * N_EMBD * 2;
    __hip_bfloat16* wpT   = (__hip_bfloat16*)ws; ws += (size_t)N_EMBD * N_EMBD * 2;
    ushort_t* Qb          = (ushort_t*)ws;       ws += (size_t)32 * TSEQ * 64 * 2;
    ushort_t* Kb          = (ushort_t*)ws;       ws += (size_t)32 * TSEQ * 64 * 2;
    ushort_t* Vb          = (ushort_t*)ws;       ws += (size_t)32 * TSEQ * 64 * 2;
    ushort_t* Vtq         = (ushort_t*)ws;       ws += (size_t)32 * 64 * TSEQ * 2;

    cvt_split_kernel<<<dim3(M_TOTAL * N_EMBD / 4 / 256), 256, 0, stream>>>(
        x, x_hi, x_lo, M_TOTAL * N_EMBD / 4);
    transpose_split_kernel<<<dim3(C3 / 32, N_EMBD / 32), 256, 0, stream>>>(
        w_attn, wqT_h, wqT_l, N_EMBD, C3);
    transpose_split_kernel<<<dim3(N_EMBD / 32, N_EMBD / 32), 256, 0, stream>>>(
        w_proj, wpT, nullptr, N_EMBD, N_EMBD);
    lora_t_part_kernel<<<dim3(M_TOTAL / 16, 4), 256, 0, stream>>>(x, la_attn, t_attn_p, N_EMBD);

    // split K and V columns (col0 >= 1024): round-5 numerics (absmax 7.8e-3).
    gemm_mfma_kernel<true><<<dim3(C3 / 128, M_TOTAL / 128), 256, 0, stream>>>(
        x_hi, x_lo, wqT_h, wqT_l, b_attn, t_attn_p, lb_attn,
        nullptr, Qb, Kb, Vb, kv_scale, kv_zp,
        M_TOTAL, C3, N_EMBD, N_EMBD, 1);

    vtrans_kernel<<<dim3(32 * (TSEQ / 64)), 256, 0, stream>>>(Vb, Vtq);

    mfma_attn_kernel<<<dim3(32 * 32), 256, 0, stream>>>(Qb, Kb, Vtq, aob);

    lora_t_part_bf16_kernel<<<dim3(M_TOTAL / 16, 4), 256, 0, stream>>>(aob, la_proj, t_proj_p, N_EMBD);

    gemm_mfma_kernel<false><<<dim3(N_EMBD / 128, M_TOTAL / 128), 256, 0, stream>>>(
        (const __hip_bfloat16*)aob, nullptr, wpT, nullptr, b_proj, t_proj_p, lb_proj,
        out, nullptr, nullptr, nullptr, nullptr, nullptr,
        M_TOTAL, N_EMBD, N_EMBD, 1 << 30, 0);
}